// Round 3
// baseline (7730.698 us; speedup 1.0000x reference)
//
#include <hip/hip_runtime.h>

#define Nn 50000
#define Ee 800000
#define KIN 133      // 2*64 + 4 + 1
#define SR 136       // lin1 LDS row stride (133 padded to 16B multiple)
#define ES 68        // node-kernel padded LDS tile stride
#define EPS 1e-5f

#define AS1 __attribute__((address_space(1)))
#define AS3 __attribute__((address_space(3)))

// async global->LDS, 16B per lane, wave-uniform LDS base
__device__ __forceinline__ void load_lds16(const float* g, float* s) {
    __builtin_amdgcn_global_load_lds((const AS1 void*)g, (AS3 void*)s, 16, 0, 0);
}

// bn+relu on a float4 with per-channel (a,c)
#define BNRELU4(V, A4, C4) \
    V.x = fmaxf(V.x * A4.x + C4.x, 0.f); \
    V.y = fmaxf(V.y * A4.y + C4.y, 0.f); \
    V.z = fmaxf(V.z * A4.z + C4.z, 0.f); \
    V.w = fmaxf(V.w * A4.w + C4.w, 0.f);

// acc row (4 floats) += AV (4 k-components) * W rows w0..w3, k-ascending order
#define FMAROW(ACCI, AV) \
    ACCI[0] += AV.x * w0.x; ACCI[0] += AV.y * w1.x; ACCI[0] += AV.z * w2.x; ACCI[0] += AV.w * w3.x; \
    ACCI[1] += AV.x * w0.y; ACCI[1] += AV.y * w1.y; ACCI[1] += AV.z * w2.y; ACCI[1] += AV.w * w3.y; \
    ACCI[2] += AV.x * w0.z; ACCI[2] += AV.y * w1.z; ACCI[2] += AV.z * w2.z; ACCI[2] += AV.w * w3.z; \
    ACCI[3] += AV.x * w0.w; ACCI[3] += AV.y * w1.w; ACCI[3] += AV.z * w2.w; ACCI[3] += AV.w * w3.w;

// ---------------------------------------------------------------- small helpers

__global__ __launch_bounds__(256) void k_lin_in(const float* __restrict__ x,
    const float* __restrict__ W, const float* __restrict__ B, float* __restrict__ h)
{
    __shared__ float Ws[11 * 64];
    __shared__ float Bs[64];
    int t = threadIdx.x;
    for (int i = t; i < 11 * 64; i += 256) Ws[i] = W[i];
    if (t < 64) Bs[t] = B[t];
    __syncthreads();
    int i = blockIdx.x * 256 + t;
    if (i < Nn * 64) {
        int n = i >> 6, c = i & 63;
        float acc = Bs[c];
        #pragma unroll
        for (int k = 0; k < 11; k++) acc += x[n * 11 + k] * Ws[k * 64 + c];
        h[i] = acc;
    }
}

__global__ __launch_bounds__(256) void k_deg(const int* __restrict__ ei, float* __restrict__ deg)
{
    int e = blockIdx.x * 256 + threadIdx.x;
    if (e < Ee) atomicAdd(&deg[ei[Ee + e]], 1.f);
}

__global__ __launch_bounds__(256) void k_cnt(const int* __restrict__ batch, float* __restrict__ cnt)
{
    int n = blockIdx.x * 256 + threadIdx.x;
    if (n < Nn) atomicAdd(&cnt[batch[n]], 1.f);
}

// ------------------------------------------------- edge lin1 (133 -> 64) + stats
// in_t layout: [e][k] rows of SR floats. Quads 0..15 = h_i (position cg^ (e&15)),
// quads 16..31 = h_j (position 16 + (cg^(e&15))), floats 128..132 = radial+ea,
// 133..135 = zero pad. Output ybuf rows quad-swizzled: quad q at q^(e&15).

__global__ __launch_bounds__(256) void k_edge_lin1(
    const float* __restrict__ h, const float* __restrict__ p,
    const float* __restrict__ ea, const int* __restrict__ ei,
    const float* __restrict__ W, const float* __restrict__ B,
    float* __restrict__ ybuf, float* __restrict__ stats_out)
{
    __shared__ float Ws[SR * 64];       // rows 0..132 from W, 133..135 zero
    __shared__ float Bs[64];
    __shared__ float in_t[64 * SR];
    int t = threadIdx.x;
    {   // stage W rows 0..131 async, row 132 + zero rows manually
        int l = t & 63, w = t >> 6;
        for (int ch = w; ch < 33; ch += 4)
            load_lds16(W + ch * 256 + l * 4, Ws + ch * 256);
    }
    if (t < 64) { Ws[8448 + t] = W[8448 + t]; Bs[t] = B[t]; }
    else        { Ws[8512 + (t - 64)] = 0.f; }              // 192 zeros
    for (int i = t; i < 64 * 3; i += 256)                    // in_t col pad
        in_t[(i / 3) * SR + 133 + (i % 3)] = 0.f;

    int tx = t & 15, ty = t >> 4;
    int cg = t & 15, eu = t >> 4;
    float ssum[4] = {0, 0, 0, 0}, ssq[4] = {0, 0, 0, 0};

    for (int tile = blockIdx.x; tile < Ee / 64; tile += gridDim.x) {
        int te = tile * 64;
        __syncthreads();                 // prev compute done (+ W vmcnt on iter 0)
        #pragma unroll
        for (int b = 0; b < 4; b++) {
            int e = eu + 16 * b;
            int sr = ei[te + e], ds = ei[Ee + te + e];
            float4 vi = *(const float4*)&h[(size_t)ds * 64 + 4 * cg];
            float4 vj = *(const float4*)&h[(size_t)sr * 64 + 4 * cg];
            int qp = (cg ^ eu) * 4;
            *(float4*)&in_t[e * SR + qp] = vi;
            *(float4*)&in_t[e * SR + 64 + qp] = vj;
        }
        if (t < 64) {
            int e = t;
            int sr = ei[te + e], ds = ei[Ee + te + e];
            float dx = p[ds * 3 + 0] - p[sr * 3 + 0];
            float dy = p[ds * 3 + 1] - p[sr * 3 + 1];
            float dz = p[ds * 3 + 2] - p[sr * 3 + 2];
            in_t[e * SR + 128] = dx * dx + dy * dy + dz * dz;
            float4 a4 = *(const float4*)&ea[(size_t)(te + e) * 4];
            in_t[e * SR + 129] = a4.x; in_t[e * SR + 130] = a4.y;
            in_t[e * SR + 131] = a4.z; in_t[e * SR + 132] = a4.w;
        }
        __syncthreads();

        float acc[4][4];
        {
            float4 b4 = *(const float4*)&Bs[4 * ty];
            #pragma unroll
            for (int i = 0; i < 4; i++) {
                acc[i][0] = b4.x; acc[i][1] = b4.y; acc[i][2] = b4.z; acc[i][3] = b4.w;
            }
        }
        #pragma unroll 2
        for (int kc = 0; kc < 34; kc++) {
            int p0 = (kc < 16) ? 4 * (kc ^ tx)
                   : (kc < 32) ? 64 + 4 * ((kc - 16) ^ tx)
                               : 4 * kc;
            float4 a0 = *(const float4*)&in_t[(tx     ) * SR + p0];
            float4 a1 = *(const float4*)&in_t[(tx + 16) * SR + p0];
            float4 a2 = *(const float4*)&in_t[(tx + 32) * SR + p0];
            float4 a3 = *(const float4*)&in_t[(tx + 48) * SR + p0];
            float4 w0 = *(const float4*)&Ws[(4 * kc + 0) * 64 + 4 * ty];
            float4 w1 = *(const float4*)&Ws[(4 * kc + 1) * 64 + 4 * ty];
            float4 w2 = *(const float4*)&Ws[(4 * kc + 2) * 64 + 4 * ty];
            float4 w3 = *(const float4*)&Ws[(4 * kc + 3) * 64 + 4 * ty];
            FMAROW(acc[0], a0); FMAROW(acc[1], a1);
            FMAROW(acc[2], a2); FMAROW(acc[3], a3);
        }
        int qp = 4 * (ty ^ tx);
        #pragma unroll
        for (int i = 0; i < 4; i++) {
            float4 o; o.x = acc[i][0]; o.y = acc[i][1]; o.z = acc[i][2]; o.w = acc[i][3];
            *(float4*)&ybuf[(size_t)(te + tx + 16 * i) * 64 + qp] = o;
            ssum[0] += o.x; ssum[1] += o.y; ssum[2] += o.z; ssum[3] += o.w;
            ssq[0] += o.x * o.x; ssq[1] += o.y * o.y; ssq[2] += o.z * o.z; ssq[3] += o.w * o.w;
        }
    }
    #pragma unroll
    for (int j = 0; j < 4; j++) {
        float s = ssum[j], q = ssq[j];
        #pragma unroll
        for (int o2 = 1; o2 < 16; o2 <<= 1) { s += __shfl_xor(s, o2); q += __shfl_xor(q, o2); }
        if (tx == 0) {
            atomicAdd(&stats_out[4 * ty + j], s);
            atomicAdd(&stats_out[64 + 4 * ty + j], q);
        }
    }
}

// --------------------------- edge: bn+relu -> lin(64->64) [+m_aggr scatter] + stats
// ybuf edge-major quad-swizzled. Tile staged linearly via global_load_lds
// (16KB contiguous), double-buffered. BN+relu folded into the FMA loop.

template<int AGGR>
__global__ __launch_bounds__(256) void k_edge_lin64(
    const float* __restrict__ stats_in, const float* __restrict__ gg,
    const float* __restrict__ be,
    const float* __restrict__ W, const float* __restrict__ B,
    const int* __restrict__ ei, float* __restrict__ magg,
    float* __restrict__ ybuf, float* __restrict__ stats_out)
{
    __shared__ float Ws[64 * 64];
    __shared__ float As[64], Cs[64], Bs[64];
    __shared__ float in_t[2 * 64 * 64];
    int t = threadIdx.x;
    int l = t & 63, w = t >> 6;
    for (int ch = w; ch < 16; ch += 4)
        load_lds16(W + ch * 256 + l * 4, Ws + ch * 256);
    if (t < 64) {
        float mean = stats_in[t] * (1.f / Ee);
        float var  = stats_in[64 + t] * (1.f / Ee) - mean * mean;
        float a = gg[t] * rsqrtf(var + EPS);
        As[t] = a; Cs[t] = be[t] - mean * a; Bs[t] = B[t];
    }
    int nt = Ee / 64;
    int tile = blockIdx.x;
    {   // stage tile0 -> buf0
        const float* src = ybuf + (size_t)tile * 4096;
        for (int ch = w; ch < 16; ch += 4)
            load_lds16(src + ch * 256 + l * 4, in_t + ch * 256);
    }
    int tx = t & 15, ty = t >> 4;
    int cur = 0;
    float ssum[4] = {0, 0, 0, 0}, ssq[4] = {0, 0, 0, 0};

    for (; tile < nt; tile += gridDim.x) {
        __syncthreads();                   // vmcnt drained: buf[cur] ready
        int te = tile * 64;
        int nxt = tile + gridDim.x;
        int dnode = 0;
        if (AGGR) dnode = ei[Ee + te + l];
        if (nxt < nt) {                    // prefetch next tile -> buf[cur^1]
            const float* src = ybuf + (size_t)nxt * 4096;
            float* dst = in_t + (cur ^ 1) * 4096;
            for (int ch = w; ch < 16; ch += 4)
                load_lds16(src + ch * 256 + l * 4, dst + ch * 256);
        }
        const float* buf = in_t + cur * 4096;
        float acc[4][4];
        {
            float4 b4 = *(const float4*)&Bs[4 * ty];
            #pragma unroll
            for (int i = 0; i < 4; i++) {
                acc[i][0] = b4.x; acc[i][1] = b4.y; acc[i][2] = b4.z; acc[i][3] = b4.w;
            }
        }
        #pragma unroll 4
        for (int kc = 0; kc < 16; kc++) {
            int p0 = 4 * (kc ^ tx);
            float4 a0 = *(const float4*)&buf[(tx     ) * 64 + p0];
            float4 a1 = *(const float4*)&buf[(tx + 16) * 64 + p0];
            float4 a2 = *(const float4*)&buf[(tx + 32) * 64 + p0];
            float4 a3 = *(const float4*)&buf[(tx + 48) * 64 + p0];
            float4 as4 = *(const float4*)&As[4 * kc];
            float4 cs4 = *(const float4*)&Cs[4 * kc];
            BNRELU4(a0, as4, cs4); BNRELU4(a1, as4, cs4);
            BNRELU4(a2, as4, cs4); BNRELU4(a3, as4, cs4);
            float4 w0 = *(const float4*)&Ws[(4 * kc + 0) * 64 + 4 * ty];
            float4 w1 = *(const float4*)&Ws[(4 * kc + 1) * 64 + 4 * ty];
            float4 w2 = *(const float4*)&Ws[(4 * kc + 2) * 64 + 4 * ty];
            float4 w3 = *(const float4*)&Ws[(4 * kc + 3) * 64 + 4 * ty];
            FMAROW(acc[0], a0); FMAROW(acc[1], a1);
            FMAROW(acc[2], a2); FMAROW(acc[3], a3);
        }
        if (AGGR) {                        // scatter normalized m into magg[dst]
            #pragma unroll
            for (int q = 0; q < 4; q++) {
                int kq = 4 * q + w;
                float4 v = *(const float4*)&buf[l * 64 + 4 * (kq ^ (l & 15))];
                float4 as4 = *(const float4*)&As[4 * kq];
                float4 cs4 = *(const float4*)&Cs[4 * kq];
                BNRELU4(v, as4, cs4);
                float* mg = &magg[(size_t)dnode * 64 + 4 * kq];
                atomicAdd(mg + 0, v.x); atomicAdd(mg + 1, v.y);
                atomicAdd(mg + 2, v.z); atomicAdd(mg + 3, v.w);
            }
        }
        int qp = 4 * (ty ^ tx);
        #pragma unroll
        for (int i = 0; i < 4; i++) {
            float4 o; o.x = acc[i][0]; o.y = acc[i][1]; o.z = acc[i][2]; o.w = acc[i][3];
            *(float4*)&ybuf[(size_t)(te + tx + 16 * i) * 64 + qp] = o;
            ssum[0] += o.x; ssum[1] += o.y; ssum[2] += o.z; ssum[3] += o.w;
            ssq[0] += o.x * o.x; ssq[1] += o.y * o.y; ssq[2] += o.z * o.z; ssq[3] += o.w * o.w;
        }
        cur ^= 1;
    }
    #pragma unroll
    for (int j = 0; j < 4; j++) {
        float s = ssum[j], q = ssq[j];
        #pragma unroll
        for (int o2 = 1; o2 < 16; o2 <<= 1) { s += __shfl_xor(s, o2); q += __shfl_xor(q, o2); }
        if (tx == 0) {
            atomicAdd(&stats_out[4 * ty + j], s);
            atomicAdd(&stats_out[64 + 4 * ty + j], q);
        }
    }
}

// ------------------------------- edge: bn+relu -> pos_lin2 (64->1) -> scatter pos update

__global__ __launch_bounds__(256) void k_pos2(
    const float* __restrict__ stats_in, const float* __restrict__ gg, const float* __restrict__ be,
    const float* __restrict__ W2, const float* __restrict__ B2,
    const float* __restrict__ p, const int* __restrict__ ei,
    const float* __restrict__ ybuf, float* __restrict__ pagg)
{
    __shared__ float As[64], Cs[64], Ws[64];
    int t = threadIdx.x;
    if (t < 64) {
        float mean = stats_in[t] * (1.f / Ee);
        float var  = stats_in[64 + t] * (1.f / Ee) - mean * mean;
        float a = gg[t] * rsqrtf(var + EPS);
        As[t] = a; Cs[t] = be[t] - mean * a; Ws[t] = W2[t];
    }
    __syncthreads();
    int e = blockIdx.x * 256 + t;
    int em = e & 15;
    const float* row = &ybuf[(size_t)e * 64];
    float acc = B2[0];
    #pragma unroll 4
    for (int u = 0; u < 16; u++) {
        float4 y = *(const float4*)&row[4 * (u ^ em)];
        acc += fmaxf(As[4 * u + 0] * y.x + Cs[4 * u + 0], 0.f) * Ws[4 * u + 0]
             + fmaxf(As[4 * u + 1] * y.y + Cs[4 * u + 1], 0.f) * Ws[4 * u + 1]
             + fmaxf(As[4 * u + 2] * y.z + Cs[4 * u + 2], 0.f) * Ws[4 * u + 2]
             + fmaxf(As[4 * u + 3] * y.w + Cs[4 * u + 3], 0.f) * Ws[4 * u + 3];
    }
    int sr = ei[e], ds = ei[Ee + e];
    float dx = p[ds * 3 + 0] - p[sr * 3 + 0];
    float dy = p[ds * 3 + 1] - p[sr * 3 + 1];
    float dz = p[ds * 3 + 2] - p[sr * 3 + 2];
    atomicAdd(&pagg[ds * 3 + 0], dx * acc);
    atomicAdd(&pagg[ds * 3 + 1], dy * acc);
    atomicAdd(&pagg[ds * 3 + 2], dz * acc);
}

// ------------------------------------------- node: [h | m_aggr] (128 -> 64) + stats

__global__ __launch_bounds__(256) void k_node_lin1(
    const float* __restrict__ h, const float* __restrict__ magg,
    const float* __restrict__ W, const float* __restrict__ B,
    float* __restrict__ yn, float* __restrict__ stats_out)
{
    __shared__ float Ws[128 * 64];
    __shared__ float Bs[64];
    __shared__ float in_t[128 * ES];
    int t = threadIdx.x;
    for (int i = t; i < 128 * 64; i += 256) Ws[i] = W[i];
    if (t < 64) Bs[t] = B[t];
    int tx = t & 15, ty = t >> 4, c = t & 63, eg = t >> 6;
    float ssum[4] = {0, 0, 0, 0}, ssq[4] = {0, 0, 0, 0};
    int nT = (Nn + 63) / 64;
    for (int tile = blockIdx.x; tile < nT; tile += gridDim.x) {
        int te = tile * 64;
        __syncthreads();
        for (int e = eg; e < 64; e += 4) {
            int n = te + e;
            bool v = n < Nn;
            in_t[c * ES + e]        = v ? h[(size_t)n * 64 + c]    : 0.f;
            in_t[(64 + c) * ES + e] = v ? magg[(size_t)n * 64 + c] : 0.f;
        }
        __syncthreads();
        float acc[4][4];
        #pragma unroll
        for (int i = 0; i < 4; i++)
            #pragma unroll
            for (int j = 0; j < 4; j++) acc[i][j] = Bs[4 * ty + j];
        for (int k = 0; k < 128; k++) {
            float av[4], wv[4];
            *(float4*)av = *(const float4*)&in_t[k * ES + 4 * tx];
            *(float4*)wv = *(const float4*)&Ws[k * 64 + 4 * ty];
            #pragma unroll
            for (int i = 0; i < 4; i++)
                #pragma unroll
                for (int j = 0; j < 4; j++)
                    acc[i][j] += av[i] * wv[j];
        }
        #pragma unroll
        for (int i = 0; i < 4; i++) {
            int n = te + 4 * tx + i;
            if (n < Nn) {
                float4 o; o.x = acc[i][0]; o.y = acc[i][1]; o.z = acc[i][2]; o.w = acc[i][3];
                *(float4*)&yn[(size_t)n * 64 + 4 * ty] = o;
                #pragma unroll
                for (int j = 0; j < 4; j++) { ssum[j] += acc[i][j]; ssq[j] += acc[i][j] * acc[i][j]; }
            }
        }
    }
    #pragma unroll
    for (int j = 0; j < 4; j++) {
        float s = ssum[j], q = ssq[j];
        #pragma unroll
        for (int o2 = 1; o2 < 16; o2 <<= 1) { s += __shfl_xor(s, o2); q += __shfl_xor(q, o2); }
        if (tx == 0) {
            atomicAdd(&stats_out[4 * ty + j], s);
            atomicAdd(&stats_out[64 + 4 * ty + j], q);
        }
    }
}

// ------------------------------------------- node: bn+relu -> lin(64->64) + stats (in-place)

__global__ __launch_bounds__(256) void k_node_lin64(
    const float* __restrict__ stats_in, const float* __restrict__ gg, const float* __restrict__ be,
    const float* __restrict__ W, const float* __restrict__ B,
    float* __restrict__ yn, float* __restrict__ stats_out)
{
    __shared__ float Ws[64 * 64];
    __shared__ float As[64], Cs[64], Bs[64];
    __shared__ float in_t[64 * ES];
    int t = threadIdx.x;
    if (t < 64) {
        float mean = stats_in[t] * (1.f / Nn);
        float var  = stats_in[64 + t] * (1.f / Nn) - mean * mean;
        float a = gg[t] * rsqrtf(var + EPS);
        As[t] = a; Cs[t] = be[t] - mean * a; Bs[t] = B[t];
    }
    for (int i = t; i < 64 * 64; i += 256) Ws[i] = W[i];
    int tx = t & 15, ty = t >> 4, c = t & 63, eg = t >> 6;
    float ssum[4] = {0, 0, 0, 0}, ssq[4] = {0, 0, 0, 0};
    int nT = (Nn + 63) / 64;
    for (int tile = blockIdx.x; tile < nT; tile += gridDim.x) {
        int te = tile * 64;
        __syncthreads();
        for (int e = eg; e < 64; e += 4) {
            int n = te + e;
            float y = (n < Nn) ? yn[(size_t)n * 64 + c] : 0.f;
            in_t[c * ES + e] = fmaxf(As[c] * y + Cs[c], 0.f);
        }
        __syncthreads();
        float acc[4][4];
        #pragma unroll
        for (int i = 0; i < 4; i++)
            #pragma unroll
            for (int j = 0; j < 4; j++) acc[i][j] = Bs[4 * ty + j];
        for (int k = 0; k < 64; k++) {
            float av[4], wv[4];
            *(float4*)av = *(const float4*)&in_t[k * ES + 4 * tx];
            *(float4*)wv = *(const float4*)&Ws[k * 64 + 4 * ty];
            #pragma unroll
            for (int i = 0; i < 4; i++)
                #pragma unroll
                for (int j = 0; j < 4; j++)
                    acc[i][j] += av[i] * wv[j];
        }
        #pragma unroll
        for (int i = 0; i < 4; i++) {
            int n = te + 4 * tx + i;
            if (n < Nn) {
                float4 o; o.x = acc[i][0]; o.y = acc[i][1]; o.z = acc[i][2]; o.w = acc[i][3];
                *(float4*)&yn[(size_t)n * 64 + 4 * ty] = o;
                #pragma unroll
                for (int j = 0; j < 4; j++) { ssum[j] += acc[i][j]; ssq[j] += acc[i][j] * acc[i][j]; }
            }
        }
    }
    #pragma unroll
    for (int j = 0; j < 4; j++) {
        float s = ssum[j], q = ssq[j];
        #pragma unroll
        for (int o2 = 1; o2 < 16; o2 <<= 1) { s += __shfl_xor(s, o2); q += __shfl_xor(q, o2); }
        if (tx == 0) {
            atomicAdd(&stats_out[4 * ty + j], s);
            atomicAdd(&stats_out[64 + 4 * ty + j], q);
        }
    }
}

// ------------------------------------------- node: residual h += relu(bn(yn)); p update

__global__ __launch_bounds__(256) void k_node_update(
    const float* __restrict__ stats_in, const float* __restrict__ gg, const float* __restrict__ be,
    const float* __restrict__ yn, float* __restrict__ h,
    const float* __restrict__ p_in, float* __restrict__ p_out,
    const float* __restrict__ pagg, const float* __restrict__ deg)
{
    int i = blockIdx.x * 256 + threadIdx.x;
    if (i < Nn * 64) {
        int c = i & 63;
        float mean = stats_in[c] * (1.f / Nn);
        float var  = stats_in[64 + c] * (1.f / Nn) - mean * mean;
        float a = gg[c] * rsqrtf(var + EPS);
        float cc = be[c] - mean * a;
        h[i] += fmaxf(a * yn[i] + cc, 0.f);
    }
    if (i < Nn * 3) {
        float dg = fmaxf(deg[i / 3], 1.f);
        p_out[i] = p_in[i] + pagg[i] / dg;
    }
}

// ------------------------------------------- pooling + prediction head

__global__ __launch_bounds__(256) void k_pool(const int* __restrict__ batch,
    const float* __restrict__ h, float* __restrict__ pool)
{
    int i = blockIdx.x * 256 + threadIdx.x;
    if (i < Nn * 64) {
        int n = i >> 6, c = i & 63;
        atomicAdd(&pool[(size_t)batch[n] * 64 + c], h[i]);
    }
}

__global__ void k_out(const float* __restrict__ pool, const float* __restrict__ cnt,
    const float* __restrict__ W, const float* __restrict__ B, float* __restrict__ out)
{
    int g = threadIdx.x;
    if (g < 64) {
        float acc = 0.f;
        for (int c = 0; c < 64; c++) acc += pool[g * 64 + c] * W[c];
        out[g] = acc / fmaxf(cnt[g], 1.f) + B[0];
    }
}

// ---------------------------------------------------------------- launch

extern "C" void kernel_launch(void* const* d_in, const int* in_sizes, int n_in,
                              void* d_out, int out_size, void* d_ws, size_t ws_size,
                              hipStream_t stream)
{
    const float* x        = (const float*)d_in[0];
    const float* pos      = (const float*)d_in[1];
    const float* ea       = (const float*)d_in[2];
    const int*   ei       = (const int*)  d_in[3];
    const int*   batch    = (const int*)  d_in[4];
    const float* lin_in_w = (const float*)d_in[5];
    const float* lin_in_b = (const float*)d_in[6];
    const float* lin_pr_w = (const float*)d_in[7];
    const float* lin_pr_b = (const float*)d_in[8];
    const float* msg_w1   = (const float*)d_in[9];
    const float* msg_b1   = (const float*)d_in[10];
    const float* msg_g1   = (const float*)d_in[11];
    const float* msg_be1  = (const float*)d_in[12];
    const float* msg_w2   = (const float*)d_in[13];
    const float* msg_b2   = (const float*)d_in[14];
    const float* msg_g2   = (const float*)d_in[15];
    const float* msg_be2  = (const float*)d_in[16];
    const float* pos_w1   = (const float*)d_in[17];
    const float* pos_b1   = (const float*)d_in[18];
    const float* pos_g    = (const float*)d_in[19];
    const float* pos_be   = (const float*)d_in[20];
    const float* pos_w2   = (const float*)d_in[21];
    const float* pos_b2   = (const float*)d_in[22];
    const float* upd_w1   = (const float*)d_in[23];
    const float* upd_b1   = (const float*)d_in[24];
    const float* upd_g1   = (const float*)d_in[25];
    const float* upd_be1  = (const float*)d_in[26];
    const float* upd_w2   = (const float*)d_in[27];
    const float* upd_b2   = (const float*)d_in[28];
    const float* upd_g2   = (const float*)d_in[29];
    const float* upd_be2  = (const float*)d_in[30];
    float* out = (float*)d_out;

    float* ws = (float*)d_ws;
    size_t o = 0;
    float* h    = ws + o; o += (size_t)Nn * 64;
    float* ybuf = ws + o; o += (size_t)Ee * 64;   // edge-major, quad-swizzled rows
    float* yn   = ws + o; o += (size_t)Nn * 64;
    float* magg = ws + o; o += (size_t)Nn * 64;   // magg + pagg contiguous (one memset)
    float* pagg = ws + o; o += (size_t)Nn * 3;
    float* pws  = ws + o; o += (size_t)Nn * 3;
    float* stats= ws + o; o += 1280;              // stats..deg contiguous (one memset)
    float* pool = ws + o; o += 64 * 64;
    float* cnt  = ws + o; o += 64;
    float* deg  = ws + o; o += Nn;
    if (ws_size < o * sizeof(float)) return;

    hipMemsetAsync(stats, 0, (size_t)(1280 + 64 * 64 + 64 + Nn) * sizeof(float), stream);
    k_lin_in<<<(Nn * 64 + 255) / 256, 256, 0, stream>>>(x, lin_in_w, lin_in_b, h);
    k_deg<<<(Ee + 255) / 256, 256, 0, stream>>>(ei, deg);
    k_cnt<<<(Nn + 255) / 256, 256, 0, stream>>>(batch, cnt);

    for (int l = 0; l < 2; l++) {
        hipMemsetAsync(magg, 0, ((size_t)Nn * 64 + (size_t)Nn * 3) * sizeof(float), stream);
        const float* pc = (l == 0) ? pos : pws;
        float* st = stats + (size_t)l * 5 * 128;
        k_edge_lin1<<<512, 256, 0, stream>>>(h, pc, ea, ei,
            msg_w1 + (size_t)l * KIN * 64, msg_b1 + l * 64, ybuf, st + 0 * 128);
        k_edge_lin64<0><<<768, 256, 0, stream>>>(st + 0 * 128, msg_g1 + l * 64, msg_be1 + l * 64,
            msg_w2 + (size_t)l * 64 * 64, msg_b2 + l * 64, ei, nullptr, ybuf, st + 1 * 128);
        k_edge_lin64<1><<<768, 256, 0, stream>>>(st + 1 * 128, msg_g2 + l * 64, msg_be2 + l * 64,
            pos_w1 + (size_t)l * 64 * 64, pos_b1 + l * 64, ei, magg, ybuf, st + 2 * 128);
        k_pos2<<<Ee / 256, 256, 0, stream>>>(st + 2 * 128, pos_g + l * 64, pos_be + l * 64,
            pos_w2 + l * 64, pos_b2 + l, pc, ei, ybuf, pagg);
        k_node_lin1<<<782, 256, 0, stream>>>(h, magg,
            upd_w1 + (size_t)l * 128 * 64, upd_b1 + l * 64, yn, st + 3 * 128);
        k_node_lin64<<<782, 256, 0, stream>>>(st + 3 * 128, upd_g1 + l * 64, upd_be1 + l * 64,
            upd_w2 + (size_t)l * 64 * 64, upd_b2 + l * 64, yn, st + 4 * 128);
        k_node_update<<<(Nn * 64 + 255) / 256, 256, 0, stream>>>(st + 4 * 128,
            upd_g2 + l * 64, upd_be2 + l * 64, yn, h, pc, pws, pagg, deg);
    }
    k_pool<<<(Nn * 64 + 255) / 256, 256, 0, stream>>>(batch, h, pool);
    k_out<<<1, 64, 0, stream>>>(pool, cnt, lin_pr_w, lin_pr_b, out);
}

// Round 4
// 7723.845 us; speedup vs baseline: 1.0009x; 1.0009x over previous
//
#include <hip/hip_runtime.h>

#define Nn 50000
#define Ee 800000
#define KIN 133      // 2*64 + 4 + 1
#define SR 136       // lin1 LDS row stride (133 padded to 16B multiple)
#define ES 68        // node-kernel padded LDS tile stride
#define EPS 1e-5f

// bn+relu on a float4 with per-channel (a,c)
#define BNRELU4(V, A4, C4) \
    V.x = fmaxf(V.x * A4.x + C4.x, 0.f); \
    V.y = fmaxf(V.y * A4.y + C4.y, 0.f); \
    V.z = fmaxf(V.z * A4.z + C4.z, 0.f); \
    V.w = fmaxf(V.w * A4.w + C4.w, 0.f);

// acc row (4 floats) += AV (4 k-components) * W rows w0..w3 (k-ascending)
#define FMAROW(ACCI, AV) \
    ACCI[0] += AV.x * w0.x; ACCI[0] += AV.y * w1.x; ACCI[0] += AV.z * w2.x; ACCI[0] += AV.w * w3.x; \
    ACCI[1] += AV.x * w0.y; ACCI[1] += AV.y * w1.y; ACCI[1] += AV.z * w2.y; ACCI[1] += AV.w * w3.y; \
    ACCI[2] += AV.x * w0.z; ACCI[2] += AV.y * w1.z; ACCI[2] += AV.z * w2.z; ACCI[2] += AV.w * w3.z; \
    ACCI[3] += AV.x * w0.w; ACCI[3] += AV.y * w1.w; ACCI[3] += AV.z * w2.w; ACCI[3] += AV.w * w3.w;

// ---------------------------------------------------------------- small helpers

__global__ __launch_bounds__(256) void k_lin_in(const float* __restrict__ x,
    const float* __restrict__ W, const float* __restrict__ B, float* __restrict__ h)
{
    __shared__ float Ws[11 * 64];
    __shared__ float Bs[64];
    int t = threadIdx.x;
    for (int i = t; i < 11 * 64; i += 256) Ws[i] = W[i];
    if (t < 64) Bs[t] = B[t];
    __syncthreads();
    int i = blockIdx.x * 256 + t;
    if (i < Nn * 64) {
        int n = i >> 6, c = i & 63;
        float acc = Bs[c];
        #pragma unroll
        for (int k = 0; k < 11; k++) acc += x[n * 11 + k] * Ws[k * 64 + c];
        h[i] = acc;
    }
}

__global__ __launch_bounds__(256) void k_deg(const int* __restrict__ ei, float* __restrict__ deg)
{
    int e = blockIdx.x * 256 + threadIdx.x;
    if (e < Ee) atomicAdd(&deg[ei[Ee + e]], 1.f);
}

__global__ __launch_bounds__(256) void k_cnt(const int* __restrict__ batch, float* __restrict__ cnt)
{
    int n = blockIdx.x * 256 + threadIdx.x;
    if (n < Nn) atomicAdd(&cnt[batch[n]], 1.f);
}

// ------------------------------------------------- edge lin1 (133 -> 64) + stats
// in_t: [e][k] rows of SR floats; channel-quad q of row e stored at quad q^(e&15)
// (h_i quads 0..15, h_j at +64 same rule), floats 128..132 radial+ea, 133..135 pad.
// Output ybuf: PLAIN edge-major [E][64].

__global__ __launch_bounds__(256) void k_edge_lin1(
    const float* __restrict__ h, const float* __restrict__ p,
    const float* __restrict__ ea, const int* __restrict__ ei,
    const float* __restrict__ W, const float* __restrict__ B,
    float* __restrict__ ybuf, float* __restrict__ stats_out)
{
    __shared__ float Ws[SR * 64];       // rows 0..132 from W, 133..135 zero
    __shared__ float Bs[64];
    __shared__ float in_t[64 * SR];
    int t = threadIdx.x;
    for (int i = t; i < 8512; i += 256) Ws[i] = W[i];          // 133*64
    for (int i = 8512 + t; i < 8704; i += 256) Ws[i] = 0.f;    // zero pad rows
    if (t < 64) Bs[t] = B[t];
    for (int i = t; i < 64 * 3; i += 256)                      // in_t col pad
        in_t[(i / 3) * SR + 133 + (i % 3)] = 0.f;

    int tx = t & 15, ty = t >> 4;
    int cg = t & 15, eu = t >> 4;       // staging: quad cg, rows eu (+16b)
    float ssum[4] = {0, 0, 0, 0}, ssq[4] = {0, 0, 0, 0};

    for (int tile = blockIdx.x; tile < Ee / 64; tile += gridDim.x) {
        int te = tile * 64;
        __syncthreads();                 // prev compute done reading in_t
        #pragma unroll
        for (int b = 0; b < 4; b++) {
            int e = eu + 16 * b;
            int sr = ei[te + e], ds = ei[Ee + te + e];
            float4 vi = *(const float4*)&h[(size_t)ds * 64 + 4 * cg];
            float4 vj = *(const float4*)&h[(size_t)sr * 64 + 4 * cg];
            int qp = (cg ^ eu) * 4;      // e&15 == eu
            *(float4*)&in_t[e * SR + qp] = vi;
            *(float4*)&in_t[e * SR + 64 + qp] = vj;
        }
        if (t < 64) {
            int e = t;
            int sr = ei[te + e], ds = ei[Ee + te + e];
            float dx = p[ds * 3 + 0] - p[sr * 3 + 0];
            float dy = p[ds * 3 + 1] - p[sr * 3 + 1];
            float dz = p[ds * 3 + 2] - p[sr * 3 + 2];
            in_t[e * SR + 128] = dx * dx + dy * dy + dz * dz;
            float4 a4 = *(const float4*)&ea[(size_t)(te + e) * 4];
            in_t[e * SR + 129] = a4.x; in_t[e * SR + 130] = a4.y;
            in_t[e * SR + 131] = a4.z; in_t[e * SR + 132] = a4.w;
        }
        __syncthreads();

        float acc[4][4];
        {
            float4 b4 = *(const float4*)&Bs[4 * ty];
            #pragma unroll
            for (int i = 0; i < 4; i++) {
                acc[i][0] = b4.x; acc[i][1] = b4.y; acc[i][2] = b4.z; acc[i][3] = b4.w;
            }
        }
        #pragma unroll 2
        for (int kc = 0; kc < 34; kc++) {
            int p0 = (kc < 16) ? 4 * (kc ^ tx)
                   : (kc < 32) ? 64 + 4 * ((kc - 16) ^ tx)
                               : 4 * kc;
            float4 a0 = *(const float4*)&in_t[(tx     ) * SR + p0];
            float4 a1 = *(const float4*)&in_t[(tx + 16) * SR + p0];
            float4 a2 = *(const float4*)&in_t[(tx + 32) * SR + p0];
            float4 a3 = *(const float4*)&in_t[(tx + 48) * SR + p0];
            float4 w0 = *(const float4*)&Ws[(4 * kc + 0) * 64 + 4 * ty];
            float4 w1 = *(const float4*)&Ws[(4 * kc + 1) * 64 + 4 * ty];
            float4 w2 = *(const float4*)&Ws[(4 * kc + 2) * 64 + 4 * ty];
            float4 w3 = *(const float4*)&Ws[(4 * kc + 3) * 64 + 4 * ty];
            FMAROW(acc[0], a0); FMAROW(acc[1], a1);
            FMAROW(acc[2], a2); FMAROW(acc[3], a3);
        }
        #pragma unroll
        for (int i = 0; i < 4; i++) {
            float4 o; o.x = acc[i][0]; o.y = acc[i][1]; o.z = acc[i][2]; o.w = acc[i][3];
            *(float4*)&ybuf[(size_t)(te + tx + 16 * i) * 64 + 4 * ty] = o;  // plain
            ssum[0] += o.x; ssum[1] += o.y; ssum[2] += o.z; ssum[3] += o.w;
            ssq[0] += o.x * o.x; ssq[1] += o.y * o.y; ssq[2] += o.z * o.z; ssq[3] += o.w * o.w;
        }
    }
    #pragma unroll
    for (int j = 0; j < 4; j++) {
        float s = ssum[j], q = ssq[j];
        #pragma unroll
        for (int o2 = 1; o2 < 16; o2 <<= 1) { s += __shfl_xor(s, o2); q += __shfl_xor(q, o2); }
        if (tx == 0) {
            atomicAdd(&stats_out[4 * ty + j], s);
            atomicAdd(&stats_out[64 + 4 * ty + j], q);
        }
    }
}

// --------------------------- edge: bn+relu -> lin(64->64) [+m_aggr scatter] + stats
// ybuf PLAIN edge-major. Staging: regular float4 loads + b128 ds_writes into
// XOR-quad-swizzled [e][64] LDS rows; register prefetch across tiles (T14).

template<int AGGR>
__global__ __launch_bounds__(256) void k_edge_lin64(
    const float* __restrict__ stats_in, const float* __restrict__ gg,
    const float* __restrict__ be,
    const float* __restrict__ W, const float* __restrict__ B,
    const int* __restrict__ ei, float* __restrict__ magg,
    float* __restrict__ ybuf, float* __restrict__ stats_out)
{
    __shared__ float Ws[64 * 64];
    __shared__ float As[64], Cs[64], Bs[64];
    __shared__ float in_t[64 * 64];
    int t = threadIdx.x;
    for (int i = t; i < 64 * 64; i += 256) Ws[i] = W[i];
    if (t < 64) {
        float mean = stats_in[t] * (1.f / Ee);
        float var  = stats_in[64 + t] * (1.f / Ee) - mean * mean;
        float a = gg[t] * rsqrtf(var + EPS);
        As[t] = a; Cs[t] = be[t] - mean * a; Bs[t] = B[t];
    }
    int tx = t & 15, ty = t >> 4;
    // staging geometry: thread t owns rows (t>>4)+16b at quad q=t&15,
    // stored at LDS quad position q^(row&15) = (t&15)^(t>>4).
    int srow = t >> 4;
    int sqp  = 4 * ((t & 15) ^ (t >> 4));
    int nt = Ee / 64;
    int tile = blockIdx.x;
    float4 r0, r1, r2, r3;
    {   // prefetch tile0
        const float* src = ybuf + (size_t)tile * 4096 + 4 * (t & 15);
        r0 = *(const float4*)&src[(srow     ) * 64];
        r1 = *(const float4*)&src[(srow + 16) * 64];
        r2 = *(const float4*)&src[(srow + 32) * 64];
        r3 = *(const float4*)&src[(srow + 48) * 64];
    }
    float ssum[4] = {0, 0, 0, 0}, ssq[4] = {0, 0, 0, 0};

    for (; tile < nt; tile += gridDim.x) {
        // write prefetched regs -> LDS (in_t free: barrier at prev iter end)
        *(float4*)&in_t[(srow     ) * 64 + sqp] = r0;
        *(float4*)&in_t[(srow + 16) * 64 + sqp] = r1;
        *(float4*)&in_t[(srow + 32) * 64 + sqp] = r2;
        *(float4*)&in_t[(srow + 48) * 64 + sqp] = r3;
        __syncthreads();                   // in_t ready
        int te = tile * 64;
        int nxt = tile + gridDim.x;
        if (nxt < nt) {                    // issue next tile's loads now
            const float* src = ybuf + (size_t)nxt * 4096 + 4 * (t & 15);
            r0 = *(const float4*)&src[(srow     ) * 64];
            r1 = *(const float4*)&src[(srow + 16) * 64];
            r2 = *(const float4*)&src[(srow + 32) * 64];
            r3 = *(const float4*)&src[(srow + 48) * 64];
        }
        float acc[4][4];
        {
            float4 b4 = *(const float4*)&Bs[4 * ty];
            #pragma unroll
            for (int i = 0; i < 4; i++) {
                acc[i][0] = b4.x; acc[i][1] = b4.y; acc[i][2] = b4.z; acc[i][3] = b4.w;
            }
        }
        #pragma unroll 4
        for (int kc = 0; kc < 16; kc++) {
            int p0 = 4 * (kc ^ tx);        // rows tx+16r: row&15 == tx
            float4 a0 = *(const float4*)&in_t[(tx     ) * 64 + p0];
            float4 a1 = *(const float4*)&in_t[(tx + 16) * 64 + p0];
            float4 a2 = *(const float4*)&in_t[(tx + 32) * 64 + p0];
            float4 a3 = *(const float4*)&in_t[(tx + 48) * 64 + p0];
            float4 as4 = *(const float4*)&As[4 * kc];
            float4 cs4 = *(const float4*)&Cs[4 * kc];
            BNRELU4(a0, as4, cs4); BNRELU4(a1, as4, cs4);
            BNRELU4(a2, as4, cs4); BNRELU4(a3, as4, cs4);
            float4 w0 = *(const float4*)&Ws[(4 * kc + 0) * 64 + 4 * ty];
            float4 w1 = *(const float4*)&Ws[(4 * kc + 1) * 64 + 4 * ty];
            float4 w2 = *(const float4*)&Ws[(4 * kc + 2) * 64 + 4 * ty];
            float4 w3 = *(const float4*)&Ws[(4 * kc + 3) * 64 + 4 * ty];
            FMAROW(acc[0], a0); FMAROW(acc[1], a1);
            FMAROW(acc[2], a2); FMAROW(acc[3], a3);
        }
        if (AGGR) {                        // scatter normalized m into magg[dst]
            int l = t & 63, w = t >> 6;
            int dnode = ei[Ee + te + l];
            #pragma unroll
            for (int q = 0; q < 4; q++) {
                int kq = 4 * q + w;
                float4 v = *(const float4*)&in_t[l * 64 + 4 * (kq ^ (l & 15))];
                float4 as4 = *(const float4*)&As[4 * kq];
                float4 cs4 = *(const float4*)&Cs[4 * kq];
                BNRELU4(v, as4, cs4);
                float* mg = &magg[(size_t)dnode * 64 + 4 * kq];
                atomicAdd(mg + 0, v.x); atomicAdd(mg + 1, v.y);
                atomicAdd(mg + 2, v.z); atomicAdd(mg + 3, v.w);
            }
        }
        #pragma unroll
        for (int i = 0; i < 4; i++) {
            float4 o; o.x = acc[i][0]; o.y = acc[i][1]; o.z = acc[i][2]; o.w = acc[i][3];
            *(float4*)&ybuf[(size_t)(te + tx + 16 * i) * 64 + 4 * ty] = o;  // plain
            ssum[0] += o.x; ssum[1] += o.y; ssum[2] += o.z; ssum[3] += o.w;
            ssq[0] += o.x * o.x; ssq[1] += o.y * o.y; ssq[2] += o.z * o.z; ssq[3] += o.w * o.w;
        }
        __syncthreads();                   // all reads of in_t done
    }
    #pragma unroll
    for (int j = 0; j < 4; j++) {
        float s = ssum[j], q = ssq[j];
        #pragma unroll
        for (int o2 = 1; o2 < 16; o2 <<= 1) { s += __shfl_xor(s, o2); q += __shfl_xor(q, o2); }
        if (tx == 0) {
            atomicAdd(&stats_out[4 * ty + j], s);
            atomicAdd(&stats_out[64 + 4 * ty + j], q);
        }
    }
}

// ------------------------------- edge: bn+relu -> pos_lin2 (64->1) -> scatter pos update

__global__ __launch_bounds__(256) void k_pos2(
    const float* __restrict__ stats_in, const float* __restrict__ gg, const float* __restrict__ be,
    const float* __restrict__ W2, const float* __restrict__ B2,
    const float* __restrict__ p, const int* __restrict__ ei,
    const float* __restrict__ ybuf, float* __restrict__ pagg)
{
    __shared__ float As[64], Cs[64], Ws[64];
    int t = threadIdx.x;
    if (t < 64) {
        float mean = stats_in[t] * (1.f / Ee);
        float var  = stats_in[64 + t] * (1.f / Ee) - mean * mean;
        float a = gg[t] * rsqrtf(var + EPS);
        As[t] = a; Cs[t] = be[t] - mean * a; Ws[t] = W2[t];
    }
    __syncthreads();
    int e = blockIdx.x * 256 + t;
    const float* row = &ybuf[(size_t)e * 64];
    float acc = B2[0];
    #pragma unroll 4
    for (int u = 0; u < 16; u++) {
        float4 y = *(const float4*)&row[4 * u];
        acc += fmaxf(As[4 * u + 0] * y.x + Cs[4 * u + 0], 0.f) * Ws[4 * u + 0]
             + fmaxf(As[4 * u + 1] * y.y + Cs[4 * u + 1], 0.f) * Ws[4 * u + 1]
             + fmaxf(As[4 * u + 2] * y.z + Cs[4 * u + 2], 0.f) * Ws[4 * u + 2]
             + fmaxf(As[4 * u + 3] * y.w + Cs[4 * u + 3], 0.f) * Ws[4 * u + 3];
    }
    int sr = ei[e], ds = ei[Ee + e];
    float dx = p[ds * 3 + 0] - p[sr * 3 + 0];
    float dy = p[ds * 3 + 1] - p[sr * 3 + 1];
    float dz = p[ds * 3 + 2] - p[sr * 3 + 2];
    atomicAdd(&pagg[ds * 3 + 0], dx * acc);
    atomicAdd(&pagg[ds * 3 + 1], dy * acc);
    atomicAdd(&pagg[ds * 3 + 2], dz * acc);
}

// ------------------------------------------- node: [h | m_aggr] (128 -> 64) + stats

__global__ __launch_bounds__(256) void k_node_lin1(
    const float* __restrict__ h, const float* __restrict__ magg,
    const float* __restrict__ W, const float* __restrict__ B,
    float* __restrict__ yn, float* __restrict__ stats_out)
{
    __shared__ float Ws[128 * 64];
    __shared__ float Bs[64];
    __shared__ float in_t[128 * ES];
    int t = threadIdx.x;
    for (int i = t; i < 128 * 64; i += 256) Ws[i] = W[i];
    if (t < 64) Bs[t] = B[t];
    int tx = t & 15, ty = t >> 4, c = t & 63, eg = t >> 6;
    float ssum[4] = {0, 0, 0, 0}, ssq[4] = {0, 0, 0, 0};
    int nT = (Nn + 63) / 64;
    for (int tile = blockIdx.x; tile < nT; tile += gridDim.x) {
        int te = tile * 64;
        __syncthreads();
        for (int e = eg; e < 64; e += 4) {
            int n = te + e;
            bool v = n < Nn;
            in_t[c * ES + e]        = v ? h[(size_t)n * 64 + c]    : 0.f;
            in_t[(64 + c) * ES + e] = v ? magg[(size_t)n * 64 + c] : 0.f;
        }
        __syncthreads();
        float acc[4][4];
        #pragma unroll
        for (int i = 0; i < 4; i++)
            #pragma unroll
            for (int j = 0; j < 4; j++) acc[i][j] = Bs[4 * ty + j];
        for (int k = 0; k < 128; k++) {
            float av[4], wv[4];
            *(float4*)av = *(const float4*)&in_t[k * ES + 4 * tx];
            *(float4*)wv = *(const float4*)&Ws[k * 64 + 4 * ty];
            #pragma unroll
            for (int i = 0; i < 4; i++)
                #pragma unroll
                for (int j = 0; j < 4; j++)
                    acc[i][j] += av[i] * wv[j];
        }
        #pragma unroll
        for (int i = 0; i < 4; i++) {
            int n = te + 4 * tx + i;
            if (n < Nn) {
                float4 o; o.x = acc[i][0]; o.y = acc[i][1]; o.z = acc[i][2]; o.w = acc[i][3];
                *(float4*)&yn[(size_t)n * 64 + 4 * ty] = o;
                #pragma unroll
                for (int j = 0; j < 4; j++) { ssum[j] += acc[i][j]; ssq[j] += acc[i][j] * acc[i][j]; }
            }
        }
    }
    #pragma unroll
    for (int j = 0; j < 4; j++) {
        float s = ssum[j], q = ssq[j];
        #pragma unroll
        for (int o2 = 1; o2 < 16; o2 <<= 1) { s += __shfl_xor(s, o2); q += __shfl_xor(q, o2); }
        if (tx == 0) {
            atomicAdd(&stats_out[4 * ty + j], s);
            atomicAdd(&stats_out[64 + 4 * ty + j], q);
        }
    }
}

// ------------------------------------------- node: bn+relu -> lin(64->64) + stats (in-place)

__global__ __launch_bounds__(256) void k_node_lin64(
    const float* __restrict__ stats_in, const float* __restrict__ gg, const float* __restrict__ be,
    const float* __restrict__ W, const float* __restrict__ B,
    float* __restrict__ yn, float* __restrict__ stats_out)
{
    __shared__ float Ws[64 * 64];
    __shared__ float As[64], Cs[64], Bs[64];
    __shared__ float in_t[64 * ES];
    int t = threadIdx.x;
    if (t < 64) {
        float mean = stats_in[t] * (1.f / Nn);
        float var  = stats_in[64 + t] * (1.f / Nn) - mean * mean;
        float a = gg[t] * rsqrtf(var + EPS);
        As[t] = a; Cs[t] = be[t] - mean * a; Bs[t] = B[t];
    }
    for (int i = t; i < 64 * 64; i += 256) Ws[i] = W[i];
    int tx = t & 15, ty = t >> 4, c = t & 63, eg = t >> 6;
    float ssum[4] = {0, 0, 0, 0}, ssq[4] = {0, 0, 0, 0};
    int nT = (Nn + 63) / 64;
    for (int tile = blockIdx.x; tile < nT; tile += gridDim.x) {
        int te = tile * 64;
        __syncthreads();
        for (int e = eg; e < 64; e += 4) {
            int n = te + e;
            float y = (n < Nn) ? yn[(size_t)n * 64 + c] : 0.f;
            in_t[c * ES + e] = fmaxf(As[c] * y + Cs[c], 0.f);
        }
        __syncthreads();
        float acc[4][4];
        #pragma unroll
        for (int i = 0; i < 4; i++)
            #pragma unroll
            for (int j = 0; j < 4; j++) acc[i][j] = Bs[4 * ty + j];
        for (int k = 0; k < 64; k++) {
            float av[4], wv[4];
            *(float4*)av = *(const float4*)&in_t[k * ES + 4 * tx];
            *(float4*)wv = *(const float4*)&Ws[k * 64 + 4 * ty];
            #pragma unroll
            for (int i = 0; i < 4; i++)
                #pragma unroll
                for (int j = 0; j < 4; j++)
                    acc[i][j] += av[i] * wv[j];
        }
        #pragma unroll
        for (int i = 0; i < 4; i++) {
            int n = te + 4 * tx + i;
            if (n < Nn) {
                float4 o; o.x = acc[i][0]; o.y = acc[i][1]; o.z = acc[i][2]; o.w = acc[i][3];
                *(float4*)&yn[(size_t)n * 64 + 4 * ty] = o;
                #pragma unroll
                for (int j = 0; j < 4; j++) { ssum[j] += acc[i][j]; ssq[j] += acc[i][j] * acc[i][j]; }
            }
        }
    }
    #pragma unroll
    for (int j = 0; j < 4; j++) {
        float s = ssum[j], q = ssq[j];
        #pragma unroll
        for (int o2 = 1; o2 < 16; o2 <<= 1) { s += __shfl_xor(s, o2); q += __shfl_xor(q, o2); }
        if (tx == 0) {
            atomicAdd(&stats_out[4 * ty + j], s);
            atomicAdd(&stats_out[64 + 4 * ty + j], q);
        }
    }
}

// ------------------------------------------- node: residual h += relu(bn(yn)); p update

__global__ __launch_bounds__(256) void k_node_update(
    const float* __restrict__ stats_in, const float* __restrict__ gg, const float* __restrict__ be,
    const float* __restrict__ yn, float* __restrict__ h,
    const float* __restrict__ p_in, float* __restrict__ p_out,
    const float* __restrict__ pagg, const float* __restrict__ deg)
{
    int i = blockIdx.x * 256 + threadIdx.x;
    if (i < Nn * 64) {
        int c = i & 63;
        float mean = stats_in[c] * (1.f / Nn);
        float var  = stats_in[64 + c] * (1.f / Nn) - mean * mean;
        float a = gg[c] * rsqrtf(var + EPS);
        float cc = be[c] - mean * a;
        h[i] += fmaxf(a * yn[i] + cc, 0.f);
    }
    if (i < Nn * 3) {
        float dg = fmaxf(deg[i / 3], 1.f);
        p_out[i] = p_in[i] + pagg[i] / dg;
    }
}

// ------------------------------------------- pooling + prediction head

__global__ __launch_bounds__(256) void k_pool(const int* __restrict__ batch,
    const float* __restrict__ h, float* __restrict__ pool)
{
    int i = blockIdx.x * 256 + threadIdx.x;
    if (i < Nn * 64) {
        int n = i >> 6, c = i & 63;
        atomicAdd(&pool[(size_t)batch[n] * 64 + c], h[i]);
    }
}

__global__ void k_out(const float* __restrict__ pool, const float* __restrict__ cnt,
    const float* __restrict__ W, const float* __restrict__ B, float* __restrict__ out)
{
    int g = threadIdx.x;
    if (g < 64) {
        float acc = 0.f;
        for (int c = 0; c < 64; c++) acc += pool[g * 64 + c] * W[c];
        out[g] = acc / fmaxf(cnt[g], 1.f) + B[0];
    }
}

// ---------------------------------------------------------------- launch

extern "C" void kernel_launch(void* const* d_in, const int* in_sizes, int n_in,
                              void* d_out, int out_size, void* d_ws, size_t ws_size,
                              hipStream_t stream)
{
    const float* x        = (const float*)d_in[0];
    const float* pos      = (const float*)d_in[1];
    const float* ea       = (const float*)d_in[2];
    const int*   ei       = (const int*)  d_in[3];
    const int*   batch    = (const int*)  d_in[4];
    const float* lin_in_w = (const float*)d_in[5];
    const float* lin_in_b = (const float*)d_in[6];
    const float* lin_pr_w = (const float*)d_in[7];
    const float* lin_pr_b = (const float*)d_in[8];
    const float* msg_w1   = (const float*)d_in[9];
    const float* msg_b1   = (const float*)d_in[10];
    const float* msg_g1   = (const float*)d_in[11];
    const float* msg_be1  = (const float*)d_in[12];
    const float* msg_w2   = (const float*)d_in[13];
    const float* msg_b2   = (const float*)d_in[14];
    const float* msg_g2   = (const float*)d_in[15];
    const float* msg_be2  = (const float*)d_in[16];
    const float* pos_w1   = (const float*)d_in[17];
    const float* pos_b1   = (const float*)d_in[18];
    const float* pos_g    = (const float*)d_in[19];
    const float* pos_be   = (const float*)d_in[20];
    const float* pos_w2   = (const float*)d_in[21];
    const float* pos_b2   = (const float*)d_in[22];
    const float* upd_w1   = (const float*)d_in[23];
    const float* upd_b1   = (const float*)d_in[24];
    const float* upd_g1   = (const float*)d_in[25];
    const float* upd_be1  = (const float*)d_in[26];
    const float* upd_w2   = (const float*)d_in[27];
    const float* upd_b2   = (const float*)d_in[28];
    const float* upd_g2   = (const float*)d_in[29];
    const float* upd_be2  = (const float*)d_in[30];
    float* out = (float*)d_out;

    float* ws = (float*)d_ws;
    size_t o = 0;
    float* h    = ws + o; o += (size_t)Nn * 64;
    float* ybuf = ws + o; o += (size_t)Ee * 64;   // plain edge-major [E][64]
    float* yn   = ws + o; o += (size_t)Nn * 64;
    float* magg = ws + o; o += (size_t)Nn * 64;   // magg + pagg contiguous (one memset)
    float* pagg = ws + o; o += (size_t)Nn * 3;
    float* pws  = ws + o; o += (size_t)Nn * 3;
    float* stats= ws + o; o += 1280;              // stats..deg contiguous (one memset)
    float* pool = ws + o; o += 64 * 64;
    float* cnt  = ws + o; o += 64;
    float* deg  = ws + o; o += Nn;
    if (ws_size < o * sizeof(float)) return;

    hipMemsetAsync(stats, 0, (size_t)(1280 + 64 * 64 + 64 + Nn) * sizeof(float), stream);
    k_lin_in<<<(Nn * 64 + 255) / 256, 256, 0, stream>>>(x, lin_in_w, lin_in_b, h);
    k_deg<<<(Ee + 255) / 256, 256, 0, stream>>>(ei, deg);
    k_cnt<<<(Nn + 255) / 256, 256, 0, stream>>>(batch, cnt);

    for (int l = 0; l < 2; l++) {
        hipMemsetAsync(magg, 0, ((size_t)Nn * 64 + (size_t)Nn * 3) * sizeof(float), stream);
        const float* pc = (l == 0) ? pos : pws;
        float* st = stats + (size_t)l * 5 * 128;
        k_edge_lin1<<<512, 256, 0, stream>>>(h, pc, ea, ei,
            msg_w1 + (size_t)l * KIN * 64, msg_b1 + l * 64, ybuf, st + 0 * 128);
        k_edge_lin64<0><<<1024, 256, 0, stream>>>(st + 0 * 128, msg_g1 + l * 64, msg_be1 + l * 64,
            msg_w2 + (size_t)l * 64 * 64, msg_b2 + l * 64, ei, nullptr, ybuf, st + 1 * 128);
        k_edge_lin64<1><<<1024, 256, 0, stream>>>(st + 1 * 128, msg_g2 + l * 64, msg_be2 + l * 64,
            pos_w1 + (size_t)l * 64 * 64, pos_b1 + l * 64, ei, magg, ybuf, st + 2 * 128);
        k_pos2<<<Ee / 256, 256, 0, stream>>>(st + 2 * 128, pos_g + l * 64, pos_be + l * 64,
            pos_w2 + l * 64, pos_b2 + l, pc, ei, ybuf, pagg);
        k_node_lin1<<<782, 256, 0, stream>>>(h, magg,
            upd_w1 + (size_t)l * 128 * 64, upd_b1 + l * 64, yn, st + 3 * 128);
        k_node_lin64<<<782, 256, 0, stream>>>(st + 3 * 128, upd_g1 + l * 64, upd_be1 + l * 64,
            upd_w2 + (size_t)l * 64 * 64, upd_b2 + l * 64, yn, st + 4 * 128);
        k_node_update<<<(Nn * 64 + 255) / 256, 256, 0, stream>>>(st + 4 * 128,
            upd_g2 + l * 64, upd_be2 + l * 64, yn, h, pc, pws, pagg, deg);
    }
    k_pool<<<(Nn * 64 + 255) / 256, 256, 0, stream>>>(batch, h, pool);
    k_out<<<1, 64, 0, stream>>>(pool, cnt, lin_pr_w, lin_pr_b, out);
}

// Round 5
// 7644.207 us; speedup vs baseline: 1.0113x; 1.0104x over previous
//
#include <hip/hip_runtime.h>

#define Nn 50000
#define Ee 800000
#define KIN 133      // 2*64 + 4 + 1
#define SR 136       // lin1 LDS row stride
#define ES 68        // node-kernel padded LDS tile stride
#define EPS 1e-5f

// bn+relu on a float4 with per-channel (a,c)
#define BNRELU4(V, A4, C4) \
    V.x = fmaxf(V.x * A4.x + C4.x, 0.f); \
    V.y = fmaxf(V.y * A4.y + C4.y, 0.f); \
    V.z = fmaxf(V.z * A4.z + C4.z, 0.f); \
    V.w = fmaxf(V.w * A4.w + C4.w, 0.f);

// acc row (4 floats) += AV (4 k-components) * W rows w0..w3 (k-ascending)
#define FMAROW(ACCI, AV) \
    ACCI[0] += AV.x * w0.x; ACCI[0] += AV.y * w1.x; ACCI[0] += AV.z * w2.x; ACCI[0] += AV.w * w3.x; \
    ACCI[1] += AV.x * w0.y; ACCI[1] += AV.y * w1.y; ACCI[1] += AV.z * w2.y; ACCI[1] += AV.w * w3.y; \
    ACCI[2] += AV.x * w0.z; ACCI[2] += AV.y * w1.z; ACCI[2] += AV.z * w2.z; ACCI[2] += AV.w * w3.z; \
    ACCI[3] += AV.x * w0.w; ACCI[3] += AV.y * w1.w; ACCI[3] += AV.z * w2.w; ACCI[3] += AV.w * w3.w;

// ---------------------------------------------------------------- small helpers

__global__ __launch_bounds__(256) void k_lin_in(const float* __restrict__ x,
    const float* __restrict__ W, const float* __restrict__ B, float* __restrict__ h)
{
    __shared__ float Ws[11 * 64];
    __shared__ float Bs[64];
    int t = threadIdx.x;
    for (int i = t; i < 11 * 64; i += 256) Ws[i] = W[i];
    if (t < 64) Bs[t] = B[t];
    __syncthreads();
    int i = blockIdx.x * 256 + t;
    if (i < Nn * 64) {
        int n = i >> 6, c = i & 63;
        float acc = Bs[c];
        #pragma unroll
        for (int k = 0; k < 11; k++) acc += x[n * 11 + k] * Ws[k * 64 + c];
        h[i] = acc;
    }
}

__global__ __launch_bounds__(256) void k_deg(const int* __restrict__ ei, float* __restrict__ deg)
{
    int e = blockIdx.x * 256 + threadIdx.x;
    if (e < Ee) atomicAdd(&deg[ei[Ee + e]], 1.f);
}

__global__ __launch_bounds__(256) void k_cnt(const int* __restrict__ batch, float* __restrict__ cnt)
{
    int n = blockIdx.x * 256 + threadIdx.x;
    if (n < Nn) atomicAdd(&cnt[batch[n]], 1.f);
}

// ------------------------------------------------- edge lin1 (133 -> 64) + stats
// in_t: [e][k] rows of SR floats; channel-quad q of row e at quad position q^(e&15)
// (h_i quads 0..15, h_j at +64 same rule), floats 128..132 radial+ea.
// After compute, in_t's flat [0,4096) region is reused as a store-bounce so each
// wave stores contiguous 1KB (full cache lines) to plain edge-major ybuf.

__global__ __launch_bounds__(256) void k_edge_lin1(
    const float* __restrict__ h, const float* __restrict__ p,
    const float* __restrict__ ea, const int* __restrict__ ei,
    const float* __restrict__ W, const float* __restrict__ B,
    float* __restrict__ ybuf, float* __restrict__ stats_out)
{
    __shared__ float Ws[KIN * 64];      // 8512
    __shared__ float Bs[64];
    __shared__ float in_t[64 * SR];     // 8704 floats
    int t = threadIdx.x;
    for (int i = t; i < KIN * 64; i += 256) Ws[i] = W[i];
    if (t < 64) Bs[t] = B[t];

    int tx = t & 15, ty = t >> 4;
    int cg = t & 15, eu = t >> 4;       // staging: quad cg, rows eu (+16b)
    int br = t >> 4;                    // store-read row base, quad t&15
    int bq = 4 * ((t & 15) ^ (t >> 4));
    float ssum[4] = {0, 0, 0, 0}, ssq[4] = {0, 0, 0, 0};

    for (int tile = blockIdx.x; tile < Ee / 64; tile += gridDim.x) {
        int te = tile * 64;
        __syncthreads();                 // prev iter's bounce reads done
        #pragma unroll
        for (int b = 0; b < 4; b++) {
            int e = eu + 16 * b;
            int sr = ei[te + e], ds = ei[Ee + te + e];
            float4 vi = *(const float4*)&h[(size_t)ds * 64 + 4 * cg];
            float4 vj = *(const float4*)&h[(size_t)sr * 64 + 4 * cg];
            int qp = (cg ^ eu) * 4;      // e&15 == eu
            *(float4*)&in_t[e * SR + qp] = vi;
            *(float4*)&in_t[e * SR + 64 + qp] = vj;
        }
        if (t < 64) {
            int e = t;
            int sr = ei[te + e], ds = ei[Ee + te + e];
            float dx = p[ds * 3 + 0] - p[sr * 3 + 0];
            float dy = p[ds * 3 + 1] - p[sr * 3 + 1];
            float dz = p[ds * 3 + 2] - p[sr * 3 + 2];
            in_t[e * SR + 128] = dx * dx + dy * dy + dz * dz;
            float4 a4 = *(const float4*)&ea[(size_t)(te + e) * 4];
            in_t[e * SR + 129] = a4.x; in_t[e * SR + 130] = a4.y;
            in_t[e * SR + 131] = a4.z; in_t[e * SR + 132] = a4.w;
        }
        __syncthreads();

        float acc[4][4];
        {
            float4 b4 = *(const float4*)&Bs[4 * ty];
            #pragma unroll
            for (int i = 0; i < 4; i++) {
                acc[i][0] = b4.x; acc[i][1] = b4.y; acc[i][2] = b4.z; acc[i][3] = b4.w;
            }
        }
        #pragma unroll 3
        for (int kc = 0; kc < 33; kc++) {   // k = 0..131
            int p0 = (kc < 16) ? 4 * (kc ^ tx)
                   : (kc < 32) ? 64 + 4 * ((kc - 16) ^ tx)
                               : 128;        // rad + ea.xyz (plain position)
            float4 a0 = *(const float4*)&in_t[(tx     ) * SR + p0];
            float4 a1 = *(const float4*)&in_t[(tx + 16) * SR + p0];
            float4 a2 = *(const float4*)&in_t[(tx + 32) * SR + p0];
            float4 a3 = *(const float4*)&in_t[(tx + 48) * SR + p0];
            float4 w0 = *(const float4*)&Ws[(4 * kc + 0) * 64 + 4 * ty];
            float4 w1 = *(const float4*)&Ws[(4 * kc + 1) * 64 + 4 * ty];
            float4 w2 = *(const float4*)&Ws[(4 * kc + 2) * 64 + 4 * ty];
            float4 w3 = *(const float4*)&Ws[(4 * kc + 3) * 64 + 4 * ty];
            FMAROW(acc[0], a0); FMAROW(acc[1], a1);
            FMAROW(acc[2], a2); FMAROW(acc[3], a3);
        }
        {   // k = 132 (ea.w) scalar tail
            float s0 = in_t[(tx     ) * SR + 132];
            float s1 = in_t[(tx + 16) * SR + 132];
            float s2 = in_t[(tx + 32) * SR + 132];
            float s3 = in_t[(tx + 48) * SR + 132];
            float4 wl = *(const float4*)&Ws[132 * 64 + 4 * ty];
            acc[0][0] += s0 * wl.x; acc[0][1] += s0 * wl.y; acc[0][2] += s0 * wl.z; acc[0][3] += s0 * wl.w;
            acc[1][0] += s1 * wl.x; acc[1][1] += s1 * wl.y; acc[1][2] += s1 * wl.z; acc[1][3] += s1 * wl.w;
            acc[2][0] += s2 * wl.x; acc[2][1] += s2 * wl.y; acc[2][2] += s2 * wl.z; acc[2][3] += s2 * wl.w;
            acc[3][0] += s3 * wl.x; acc[3][1] += s3 * wl.y; acc[3][2] += s3 * wl.z; acc[3][3] += s3 * wl.w;
        }
        #pragma unroll
        for (int i = 0; i < 4; i++) {
            #pragma unroll
            for (int j = 0; j < 4; j++) { ssum[j] += acc[i][j]; ssq[j] += acc[i][j] * acc[i][j]; }
        }
        __syncthreads();                 // all in_t reads done
        #pragma unroll
        for (int i = 0; i < 4; i++) {    // bounce acc -> flat [0,4096) of in_t
            float4 o; o.x = acc[i][0]; o.y = acc[i][1]; o.z = acc[i][2]; o.w = acc[i][3];
            *(float4*)&in_t[(tx + 16 * i) * 64 + 4 * (ty ^ tx)] = o;
        }
        __syncthreads();                 // bounce ready
        #pragma unroll
        for (int r = 0; r < 4; r++) {    // wave-contiguous 1KB full-line stores
            float4 o = *(const float4*)&in_t[(16 * r + br) * 64 + bq];
            *(float4*)&ybuf[(size_t)tile * 4096 + r * 1024 + 4 * t] = o;
        }
    }
    #pragma unroll
    for (int j = 0; j < 4; j++) {
        float s = ssum[j], q = ssq[j];
        #pragma unroll
        for (int o2 = 1; o2 < 16; o2 <<= 1) { s += __shfl_xor(s, o2); q += __shfl_xor(q, o2); }
        if (tx == 0) {
            atomicAdd(&stats_out[4 * ty + j], s);
            atomicAdd(&stats_out[64 + 4 * ty + j], q);
        }
    }
}

// --------------------------- edge: bn+relu -> lin(64->64) [+m_aggr scatter] + stats
// ybuf PLAIN edge-major. In-iteration staging (float4 loads + swizzled b128
// ds_writes, verified conflict-free). No cross-tile prefetch. Output bounced
// through in_t so global stores are wave-contiguous full cache lines.

template<int AGGR>
__global__ __launch_bounds__(256) void k_edge_lin64(
    const float* __restrict__ stats_in, const float* __restrict__ gg,
    const float* __restrict__ be,
    const float* __restrict__ W, const float* __restrict__ B,
    const int* __restrict__ ei, float* __restrict__ magg,
    float* __restrict__ ybuf, float* __restrict__ stats_out)
{
    __shared__ float Ws[64 * 64];
    __shared__ float As[64], Cs[64], Bs[64];
    __shared__ float in_t[64 * 64];
    int t = threadIdx.x;
    for (int i = t; i < 64 * 64; i += 256) Ws[i] = W[i];
    if (t < 64) {
        float mean = stats_in[t] * (1.f / Ee);
        float var  = stats_in[64 + t] * (1.f / Ee) - mean * mean;
        float a = gg[t] * rsqrtf(var + EPS);
        As[t] = a; Cs[t] = be[t] - mean * a; Bs[t] = B[t];
    }
    int tx = t & 15, ty = t >> 4;
    int srow = t >> 4;
    int sqp  = 4 * ((t & 15) ^ (t >> 4));
    int nt = Ee / 64;
    float ssum[4] = {0, 0, 0, 0}, ssq[4] = {0, 0, 0, 0};

    for (int tile = blockIdx.x; tile < nt; tile += gridDim.x) {
        const float* src = ybuf + (size_t)tile * 4096 + 4 * (t & 15);
        float4 r0 = *(const float4*)&src[(srow     ) * 64];
        float4 r1 = *(const float4*)&src[(srow + 16) * 64];
        float4 r2 = *(const float4*)&src[(srow + 32) * 64];
        float4 r3 = *(const float4*)&src[(srow + 48) * 64];
        __syncthreads();                   // prev iter's bounce reads done
        *(float4*)&in_t[(srow     ) * 64 + sqp] = r0;
        *(float4*)&in_t[(srow + 16) * 64 + sqp] = r1;
        *(float4*)&in_t[(srow + 32) * 64 + sqp] = r2;
        *(float4*)&in_t[(srow + 48) * 64 + sqp] = r3;
        __syncthreads();                   // in_t ready
        int te = tile * 64;
        float acc[4][4];
        {
            float4 b4 = *(const float4*)&Bs[4 * ty];
            #pragma unroll
            for (int i = 0; i < 4; i++) {
                acc[i][0] = b4.x; acc[i][1] = b4.y; acc[i][2] = b4.z; acc[i][3] = b4.w;
            }
        }
        #pragma unroll 4
        for (int kc = 0; kc < 16; kc++) {
            int p0 = 4 * (kc ^ tx);        // rows tx+16r: row&15 == tx
            float4 a0 = *(const float4*)&in_t[(tx     ) * 64 + p0];
            float4 a1 = *(const float4*)&in_t[(tx + 16) * 64 + p0];
            float4 a2 = *(const float4*)&in_t[(tx + 32) * 64 + p0];
            float4 a3 = *(const float4*)&in_t[(tx + 48) * 64 + p0];
            float4 as4 = *(const float4*)&As[4 * kc];
            float4 cs4 = *(const float4*)&Cs[4 * kc];
            BNRELU4(a0, as4, cs4); BNRELU4(a1, as4, cs4);
            BNRELU4(a2, as4, cs4); BNRELU4(a3, as4, cs4);
            float4 w0 = *(const float4*)&Ws[(4 * kc + 0) * 64 + 4 * ty];
            float4 w1 = *(const float4*)&Ws[(4 * kc + 1) * 64 + 4 * ty];
            float4 w2 = *(const float4*)&Ws[(4 * kc + 2) * 64 + 4 * ty];
            float4 w3 = *(const float4*)&Ws[(4 * kc + 3) * 64 + 4 * ty];
            FMAROW(acc[0], a0); FMAROW(acc[1], a1);
            FMAROW(acc[2], a2); FMAROW(acc[3], a3);
        }
        if (AGGR) {                        // scatter normalized m into magg[dst]
            int l = t & 63, w = t >> 6;
            int dnode = ei[Ee + te + l];
            #pragma unroll
            for (int q = 0; q < 4; q++) {
                int kq = 4 * q + w;
                float4 v = *(const float4*)&in_t[l * 64 + 4 * (kq ^ (l & 15))];
                float4 as4 = *(const float4*)&As[4 * kq];
                float4 cs4 = *(const float4*)&Cs[4 * kq];
                BNRELU4(v, as4, cs4);
                float* mg = &magg[(size_t)dnode * 64 + 4 * kq];
                atomicAdd(mg + 0, v.x); atomicAdd(mg + 1, v.y);
                atomicAdd(mg + 2, v.z); atomicAdd(mg + 3, v.w);
            }
        }
        #pragma unroll
        for (int i = 0; i < 4; i++) {
            #pragma unroll
            for (int j = 0; j < 4; j++) { ssum[j] += acc[i][j]; ssq[j] += acc[i][j] * acc[i][j]; }
        }
        __syncthreads();                   // all in_t reads done
        #pragma unroll
        for (int i = 0; i < 4; i++) {      // bounce acc -> in_t
            float4 o; o.x = acc[i][0]; o.y = acc[i][1]; o.z = acc[i][2]; o.w = acc[i][3];
            *(float4*)&in_t[(tx + 16 * i) * 64 + 4 * (ty ^ tx)] = o;
        }
        __syncthreads();                   // bounce ready
        #pragma unroll
        for (int r = 0; r < 4; r++) {      // wave-contiguous 1KB full-line stores
            float4 o = *(const float4*)&in_t[(16 * r + srow) * 64 + sqp];
            *(float4*)&ybuf[(size_t)tile * 4096 + r * 1024 + 4 * t] = o;
        }
    }
    #pragma unroll
    for (int j = 0; j < 4; j++) {
        float s = ssum[j], q = ssq[j];
        #pragma unroll
        for (int o2 = 1; o2 < 16; o2 <<= 1) { s += __shfl_xor(s, o2); q += __shfl_xor(q, o2); }
        if (tx == 0) {
            atomicAdd(&stats_out[4 * ty + j], s);
            atomicAdd(&stats_out[64 + 4 * ty + j], q);
        }
    }
}

// ------------------------------- edge: bn+relu -> pos_lin2 (64->1) -> scatter pos update

__global__ __launch_bounds__(256) void k_pos2(
    const float* __restrict__ stats_in, const float* __restrict__ gg, const float* __restrict__ be,
    const float* __restrict__ W2, const float* __restrict__ B2,
    const float* __restrict__ p, const int* __restrict__ ei,
    const float* __restrict__ ybuf, float* __restrict__ pagg)
{
    __shared__ float As[64], Cs[64], Ws[64];
    int t = threadIdx.x;
    if (t < 64) {
        float mean = stats_in[t] * (1.f / Ee);
        float var  = stats_in[64 + t] * (1.f / Ee) - mean * mean;
        float a = gg[t] * rsqrtf(var + EPS);
        As[t] = a; Cs[t] = be[t] - mean * a; Ws[t] = W2[t];
    }
    __syncthreads();
    int e = blockIdx.x * 256 + t;
    const float* row = &ybuf[(size_t)e * 64];
    float acc = B2[0];
    #pragma unroll 4
    for (int u = 0; u < 16; u++) {
        float4 y = *(const float4*)&row[4 * u];
        acc += fmaxf(As[4 * u + 0] * y.x + Cs[4 * u + 0], 0.f) * Ws[4 * u + 0]
             + fmaxf(As[4 * u + 1] * y.y + Cs[4 * u + 1], 0.f) * Ws[4 * u + 1]
             + fmaxf(As[4 * u + 2] * y.z + Cs[4 * u + 2], 0.f) * Ws[4 * u + 2]
             + fmaxf(As[4 * u + 3] * y.w + Cs[4 * u + 3], 0.f) * Ws[4 * u + 3];
    }
    int sr = ei[e], ds = ei[Ee + e];
    float dx = p[ds * 3 + 0] - p[sr * 3 + 0];
    float dy = p[ds * 3 + 1] - p[sr * 3 + 1];
    float dz = p[ds * 3 + 2] - p[sr * 3 + 2];
    atomicAdd(&pagg[ds * 3 + 0], dx * acc);
    atomicAdd(&pagg[ds * 3 + 1], dy * acc);
    atomicAdd(&pagg[ds * 3 + 2], dz * acc);
}

// ------------------------------------------- node: [h | m_aggr] (128 -> 64) + stats

__global__ __launch_bounds__(256) void k_node_lin1(
    const float* __restrict__ h, const float* __restrict__ magg,
    const float* __restrict__ W, const float* __restrict__ B,
    float* __restrict__ yn, float* __restrict__ stats_out)
{
    __shared__ float Ws[128 * 64];
    __shared__ float Bs[64];
    __shared__ float in_t[128 * ES];
    int t = threadIdx.x;
    for (int i = t; i < 128 * 64; i += 256) Ws[i] = W[i];
    if (t < 64) Bs[t] = B[t];
    int tx = t & 15, ty = t >> 4, c = t & 63, eg = t >> 6;
    float ssum[4] = {0, 0, 0, 0}, ssq[4] = {0, 0, 0, 0};
    int nT = (Nn + 63) / 64;
    for (int tile = blockIdx.x; tile < nT; tile += gridDim.x) {
        int te = tile * 64;
        __syncthreads();
        for (int e = eg; e < 64; e += 4) {
            int n = te + e;
            bool v = n < Nn;
            in_t[c * ES + e]        = v ? h[(size_t)n * 64 + c]    : 0.f;
            in_t[(64 + c) * ES + e] = v ? magg[(size_t)n * 64 + c] : 0.f;
        }
        __syncthreads();
        float acc[4][4];
        #pragma unroll
        for (int i = 0; i < 4; i++)
            #pragma unroll
            for (int j = 0; j < 4; j++) acc[i][j] = Bs[4 * ty + j];
        for (int k = 0; k < 128; k++) {
            float av[4], wv[4];
            *(float4*)av = *(const float4*)&in_t[k * ES + 4 * tx];
            *(float4*)wv = *(const float4*)&Ws[k * 64 + 4 * ty];
            #pragma unroll
            for (int i = 0; i < 4; i++)
                #pragma unroll
                for (int j = 0; j < 4; j++)
                    acc[i][j] += av[i] * wv[j];
        }
        #pragma unroll
        for (int i = 0; i < 4; i++) {
            int n = te + 4 * tx + i;
            if (n < Nn) {
                float4 o; o.x = acc[i][0]; o.y = acc[i][1]; o.z = acc[i][2]; o.w = acc[i][3];
                *(float4*)&yn[(size_t)n * 64 + 4 * ty] = o;
                #pragma unroll
                for (int j = 0; j < 4; j++) { ssum[j] += acc[i][j]; ssq[j] += acc[i][j] * acc[i][j]; }
            }
        }
    }
    #pragma unroll
    for (int j = 0; j < 4; j++) {
        float s = ssum[j], q = ssq[j];
        #pragma unroll
        for (int o2 = 1; o2 < 16; o2 <<= 1) { s += __shfl_xor(s, o2); q += __shfl_xor(q, o2); }
        if (tx == 0) {
            atomicAdd(&stats_out[4 * ty + j], s);
            atomicAdd(&stats_out[64 + 4 * ty + j], q);
        }
    }
}

// ------------------------------------------- node: bn+relu -> lin(64->64) + stats (in-place)

__global__ __launch_bounds__(256) void k_node_lin64(
    const float* __restrict__ stats_in, const float* __restrict__ gg, const float* __restrict__ be,
    const float* __restrict__ W, const float* __restrict__ B,
    float* __restrict__ yn, float* __restrict__ stats_out)
{
    __shared__ float Ws[64 * 64];
    __shared__ float As[64], Cs[64], Bs[64];
    __shared__ float in_t[64 * ES];
    int t = threadIdx.x;
    if (t < 64) {
        float mean = stats_in[t] * (1.f / Nn);
        float var  = stats_in[64 + t] * (1.f / Nn) - mean * mean;
        float a = gg[t] * rsqrtf(var + EPS);
        As[t] = a; Cs[t] = be[t] - mean * a; Bs[t] = B[t];
    }
    for (int i = t; i < 64 * 64; i += 256) Ws[i] = W[i];
    int tx = t & 15, ty = t >> 4, c = t & 63, eg = t >> 6;
    float ssum[4] = {0, 0, 0, 0}, ssq[4] = {0, 0, 0, 0};
    int nT = (Nn + 63) / 64;
    for (int tile = blockIdx.x; tile < nT; tile += gridDim.x) {
        int te = tile * 64;
        __syncthreads();
        for (int e = eg; e < 64; e += 4) {
            int n = te + e;
            float y = (n < Nn) ? yn[(size_t)n * 64 + c] : 0.f;
            in_t[c * ES + e] = fmaxf(As[c] * y + Cs[c], 0.f);
        }
        __syncthreads();
        float acc[4][4];
        #pragma unroll
        for (int i = 0; i < 4; i++)
            #pragma unroll
            for (int j = 0; j < 4; j++) acc[i][j] = Bs[4 * ty + j];
        for (int k = 0; k < 64; k++) {
            float av[4], wv[4];
            *(float4*)av = *(const float4*)&in_t[k * ES + 4 * tx];
            *(float4*)wv = *(const float4*)&Ws[k * 64 + 4 * ty];
            #pragma unroll
            for (int i = 0; i < 4; i++)
                #pragma unroll
                for (int j = 0; j < 4; j++)
                    acc[i][j] += av[i] * wv[j];
        }
        #pragma unroll
        for (int i = 0; i < 4; i++) {
            int n = te + 4 * tx + i;
            if (n < Nn) {
                float4 o; o.x = acc[i][0]; o.y = acc[i][1]; o.z = acc[i][2]; o.w = acc[i][3];
                *(float4*)&yn[(size_t)n * 64 + 4 * ty] = o;
                #pragma unroll
                for (int j = 0; j < 4; j++) { ssum[j] += acc[i][j]; ssq[j] += acc[i][j] * acc[i][j]; }
            }
        }
    }
    #pragma unroll
    for (int j = 0; j < 4; j++) {
        float s = ssum[j], q = ssq[j];
        #pragma unroll
        for (int o2 = 1; o2 < 16; o2 <<= 1) { s += __shfl_xor(s, o2); q += __shfl_xor(q, o2); }
        if (tx == 0) {
            atomicAdd(&stats_out[4 * ty + j], s);
            atomicAdd(&stats_out[64 + 4 * ty + j], q);
        }
    }
}

// ------------------------------------------- node: residual h += relu(bn(yn)); p update

__global__ __launch_bounds__(256) void k_node_update(
    const float* __restrict__ stats_in, const float* __restrict__ gg, const float* __restrict__ be,
    const float* __restrict__ yn, float* __restrict__ h,
    const float* __restrict__ p_in, float* __restrict__ p_out,
    const float* __restrict__ pagg, const float* __restrict__ deg)
{
    int i = blockIdx.x * 256 + threadIdx.x;
    if (i < Nn * 64) {
        int c = i & 63;
        float mean = stats_in[c] * (1.f / Nn);
        float var  = stats_in[64 + c] * (1.f / Nn) - mean * mean;
        float a = gg[c] * rsqrtf(var + EPS);
        float cc = be[c] - mean * a;
        h[i] += fmaxf(a * yn[i] + cc, 0.f);
    }
    if (i < Nn * 3) {
        float dg = fmaxf(deg[i / 3], 1.f);
        p_out[i] = p_in[i] + pagg[i] / dg;
    }
}

// ------------------------------------------- pooling + prediction head

__global__ __launch_bounds__(256) void k_pool(const int* __restrict__ batch,
    const float* __restrict__ h, float* __restrict__ pool)
{
    int i = blockIdx.x * 256 + threadIdx.x;
    if (i < Nn * 64) {
        int n = i >> 6, c = i & 63;
        atomicAdd(&pool[(size_t)batch[n] * 64 + c], h[i]);
    }
}

__global__ void k_out(const float* __restrict__ pool, const float* __restrict__ cnt,
    const float* __restrict__ W, const float* __restrict__ B, float* __restrict__ out)
{
    int g = threadIdx.x;
    if (g < 64) {
        float acc = 0.f;
        for (int c = 0; c < 64; c++) acc += pool[g * 64 + c] * W[c];
        out[g] = acc / fmaxf(cnt[g], 1.f) + B[0];
    }
}

// ---------------------------------------------------------------- launch

extern "C" void kernel_launch(void* const* d_in, const int* in_sizes, int n_in,
                              void* d_out, int out_size, void* d_ws, size_t ws_size,
                              hipStream_t stream)
{
    const float* x        = (const float*)d_in[0];
    const float* pos      = (const float*)d_in[1];
    const float* ea       = (const float*)d_in[2];
    const int*   ei       = (const int*)  d_in[3];
    const int*   batch    = (const int*)  d_in[4];
    const float* lin_in_w = (const float*)d_in[5];
    const float* lin_in_b = (const float*)d_in[6];
    const float* lin_pr_w = (const float*)d_in[7];
    const float* lin_pr_b = (const float*)d_in[8];
    const float* msg_w1   = (const float*)d_in[9];
    const float* msg_b1   = (const float*)d_in[10];
    const float* msg_g1   = (const float*)d_in[11];
    const float* msg_be1  = (const float*)d_in[12];
    const float* msg_w2   = (const float*)d_in[13];
    const float* msg_b2   = (const float*)d_in[14];
    const float* msg_g2   = (const float*)d_in[15];
    const float* msg_be2  = (const float*)d_in[16];
    const float* pos_w1   = (const float*)d_in[17];
    const float* pos_b1   = (const float*)d_in[18];
    const float* pos_g    = (const float*)d_in[19];
    const float* pos_be   = (const float*)d_in[20];
    const float* pos_w2   = (const float*)d_in[21];
    const float* pos_b2   = (const float*)d_in[22];
    const float* upd_w1   = (const float*)d_in[23];
    const float* upd_b1   = (const float*)d_in[24];
    const float* upd_g1   = (const float*)d_in[25];
    const float* upd_be1  = (const float*)d_in[26];
    const float* upd_w2   = (const float*)d_in[27];
    const float* upd_b2   = (const float*)d_in[28];
    const float* upd_g2   = (const float*)d_in[29];
    const float* upd_be2  = (const float*)d_in[30];
    float* out = (float*)d_out;

    float* ws = (float*)d_ws;
    size_t o = 0;
    float* h    = ws + o; o += (size_t)Nn * 64;
    float* ybuf = ws + o; o += (size_t)Ee * 64;   // plain edge-major [E][64]
    float* yn   = ws + o; o += (size_t)Nn * 64;
    float* magg = ws + o; o += (size_t)Nn * 64;   // magg + pagg contiguous (one memset)
    float* pagg = ws + o; o += (size_t)Nn * 3;
    float* pws  = ws + o; o += (size_t)Nn * 3;
    float* stats= ws + o; o += 1280;              // stats..deg contiguous (one memset)
    float* pool = ws + o; o += 64 * 64;
    float* cnt  = ws + o; o += 64;
    float* deg  = ws + o; o += Nn;
    if (ws_size < o * sizeof(float)) return;

    hipMemsetAsync(stats, 0, (size_t)(1280 + 64 * 64 + 64 + Nn) * sizeof(float), stream);
    k_lin_in<<<(Nn * 64 + 255) / 256, 256, 0, stream>>>(x, lin_in_w, lin_in_b, h);
    k_deg<<<(Ee + 255) / 256, 256, 0, stream>>>(ei, deg);
    k_cnt<<<(Nn + 255) / 256, 256, 0, stream>>>(batch, cnt);

    for (int l = 0; l < 2; l++) {
        hipMemsetAsync(magg, 0, ((size_t)Nn * 64 + (size_t)Nn * 3) * sizeof(float), stream);
        const float* pc = (l == 0) ? pos : pws;
        float* st = stats + (size_t)l * 5 * 128;
        k_edge_lin1<<<512, 256, 0, stream>>>(h, pc, ea, ei,
            msg_w1 + (size_t)l * KIN * 64, msg_b1 + l * 64, ybuf, st + 0 * 128);
        k_edge_lin64<0><<<1024, 256, 0, stream>>>(st + 0 * 128, msg_g1 + l * 64, msg_be1 + l * 64,
            msg_w2 + (size_t)l * 64 * 64, msg_b2 + l * 64, ei, nullptr, ybuf, st + 1 * 128);
        k_edge_lin64<1><<<1024, 256, 0, stream>>>(st + 1 * 128, msg_g2 + l * 64, msg_be2 + l * 64,
            pos_w1 + (size_t)l * 64 * 64, pos_b1 + l * 64, ei, magg, ybuf, st + 2 * 128);
        k_pos2<<<Ee / 256, 256, 0, stream>>>(st + 2 * 128, pos_g + l * 64, pos_be + l * 64,
            pos_w2 + l * 64, pos_b2 + l, pc, ei, ybuf, pagg);
        k_node_lin1<<<782, 256, 0, stream>>>(h, magg,
            upd_w1 + (size_t)l * 128 * 64, upd_b1 + l * 64, yn, st + 3 * 128);
        k_node_lin64<<<782, 256, 0, stream>>>(st + 3 * 128, upd_g1 + l * 64, upd_be1 + l * 64,
            upd_w2 + (size_t)l * 64 * 64, upd_b2 + l * 64, yn, st + 4 * 128);
        k_node_update<<<(Nn * 64 + 255) / 256, 256, 0, stream>>>(st + 4 * 128,
            upd_g2 + l * 64, upd_be2 + l * 64, yn, h, pc, pws, pagg, deg);
    }
    k_pool<<<(Nn * 64 + 255) / 256, 256, 0, stream>>>(batch, h, pool);
    k_out<<<1, 64, 0, stream>>>(pool, cnt, lin_pr_w, lin_pr_b, out);
}

// Round 6
// 7516.022 us; speedup vs baseline: 1.0286x; 1.0171x over previous
//
#include <hip/hip_runtime.h>

#define Nn 50000
#define Ee 800000
#define KIN 133      // 2*64 + 4 + 1
#define ES 68        // lin1/node LDS tile stride (padded)
#define EPS 1e-5f

typedef unsigned short u16;

// bf16 round-to-nearest-even pack/unpack (manual, no header dependency)
__device__ __forceinline__ u16 f2bf(float f) {
    union { float f; unsigned u; } v; v.f = f;
    unsigned r = (v.u + 0x7FFFu + ((v.u >> 16) & 1u)) >> 16;
    return (u16)r;
}
__device__ __forceinline__ float bf2f(u16 s) {
    union { unsigned u; float f; } v; v.u = ((unsigned)s) << 16;
    return v.f;
}

// bn+relu on a float4 with per-channel (a,c)
#define BNRELU4(V, A4, C4) \
    V.x = fmaxf(V.x * A4.x + C4.x, 0.f); \
    V.y = fmaxf(V.y * A4.y + C4.y, 0.f); \
    V.z = fmaxf(V.z * A4.z + C4.z, 0.f); \
    V.w = fmaxf(V.w * A4.w + C4.w, 0.f);

// acc row (4 floats) += AV (4 k-components) * W rows w0..w3 (k-ascending)
#define FMAROW(ACCI, AV) \
    ACCI[0] += AV.x * w0.x; ACCI[0] += AV.y * w1.x; ACCI[0] += AV.z * w2.x; ACCI[0] += AV.w * w3.x; \
    ACCI[1] += AV.x * w0.y; ACCI[1] += AV.y * w1.y; ACCI[1] += AV.z * w2.y; ACCI[1] += AV.w * w3.y; \
    ACCI[2] += AV.x * w0.z; ACCI[2] += AV.y * w1.z; ACCI[2] += AV.z * w2.z; ACCI[2] += AV.w * w3.z; \
    ACCI[3] += AV.x * w0.w; ACCI[3] += AV.y * w1.w; ACCI[3] += AV.z * w2.w; ACCI[3] += AV.w * w3.w;

// ---------------------------------------------------------------- small helpers

__global__ __launch_bounds__(256) void k_lin_in(const float* __restrict__ x,
    const float* __restrict__ W, const float* __restrict__ B, float* __restrict__ h)
{
    __shared__ float Ws[11 * 64];
    __shared__ float Bs[64];
    int t = threadIdx.x;
    for (int i = t; i < 11 * 64; i += 256) Ws[i] = W[i];
    if (t < 64) Bs[t] = B[t];
    __syncthreads();
    int i = blockIdx.x * 256 + t;
    if (i < Nn * 64) {
        int n = i >> 6, c = i & 63;
        float acc = Bs[c];
        #pragma unroll
        for (int k = 0; k < 11; k++) acc += x[n * 11 + k] * Ws[k * 64 + c];
        h[i] = acc;
    }
}

__global__ __launch_bounds__(256) void k_deg(const int* __restrict__ ei, float* __restrict__ deg)
{
    int e = blockIdx.x * 256 + threadIdx.x;
    if (e < Ee) atomicAdd(&deg[ei[Ee + e]], 1.f);
}

__global__ __launch_bounds__(256) void k_cnt(const int* __restrict__ batch, float* __restrict__ cnt)
{
    int n = blockIdx.x * 256 + threadIdx.x;
    if (n < Nn) atomicAdd(&cnt[batch[n]], 1.f);
}

// ------------------------------------------------- edge lin1 (133 -> 64) + stats
// R1-proven structure; output now bf16 to ybA (stats from the rounded values).

__global__ __launch_bounds__(256) void k_edge_lin1(
    const float* __restrict__ h, const float* __restrict__ p,
    const float* __restrict__ ea, const int* __restrict__ ei,
    const float* __restrict__ W, const float* __restrict__ B,
    u16* __restrict__ yb, float* __restrict__ stats_out)
{
    __shared__ float Ws[KIN * 64];
    __shared__ float Bs[64];
    __shared__ float in_t[KIN * ES];     // [k][e] transposed tile
    int t = threadIdx.x;
    for (int i = t; i < KIN * 64; i += 256) Ws[i] = W[i];
    if (t < 64) Bs[t] = B[t];
    int tx = t & 15, ty = t >> 4;        // compute: e0=4*tx, c0=4*ty
    int c = t & 63, eg = t >> 6;         // staging roles
    float ssum[4] = {0, 0, 0, 0}, ssq[4] = {0, 0, 0, 0};
    for (int tile = blockIdx.x; tile < Ee / 64; tile += gridDim.x) {
        int te = tile * 64;
        __syncthreads();
        for (int e = eg; e < 64; e += 4) {
            int sr = ei[te + e], ds = ei[Ee + te + e];
            in_t[c * ES + e]        = h[(size_t)ds * 64 + c];   // h_i = h[dst]
            in_t[(64 + c) * ES + e] = h[(size_t)sr * 64 + c];   // h_j = h[src]
        }
        if (t < 64) {
            int e = t;
            int sr = ei[te + e], ds = ei[Ee + te + e];
            float dx = p[ds * 3 + 0] - p[sr * 3 + 0];
            float dy = p[ds * 3 + 1] - p[sr * 3 + 1];
            float dz = p[ds * 3 + 2] - p[sr * 3 + 2];
            in_t[128 * ES + e] = dx * dx + dy * dy + dz * dz;
            float4 a4 = *(const float4*)&ea[(size_t)(te + e) * 4];
            in_t[129 * ES + e] = a4.x;
            in_t[130 * ES + e] = a4.y;
            in_t[131 * ES + e] = a4.z;
            in_t[132 * ES + e] = a4.w;
        }
        __syncthreads();
        float acc[4][4];
        #pragma unroll
        for (int i = 0; i < 4; i++)
            #pragma unroll
            for (int j = 0; j < 4; j++) acc[i][j] = Bs[4 * ty + j];
        for (int k = 0; k < KIN; k++) {
            float av[4], wv[4];
            *(float4*)av = *(const float4*)&in_t[k * ES + 4 * tx];
            *(float4*)wv = *(const float4*)&Ws[k * 64 + 4 * ty];
            #pragma unroll
            for (int i = 0; i < 4; i++)
                #pragma unroll
                for (int j = 0; j < 4; j++)
                    acc[i][j] += av[i] * wv[j];
        }
        #pragma unroll
        for (int i = 0; i < 4; i++) {
            size_t e = (size_t)te + 4 * tx + i;
            ushort4 o;
            o.x = f2bf(acc[i][0]); o.y = f2bf(acc[i][1]);
            o.z = f2bf(acc[i][2]); o.w = f2bf(acc[i][3]);
            *(ushort4*)&yb[e * 64 + 4 * ty] = o;
            float r0 = bf2f(o.x), r1 = bf2f(o.y), r2 = bf2f(o.z), r3 = bf2f(o.w);
            ssum[0] += r0; ssum[1] += r1; ssum[2] += r2; ssum[3] += r3;
            ssq[0] += r0 * r0; ssq[1] += r1 * r1; ssq[2] += r2 * r2; ssq[3] += r3 * r3;
        }
    }
    #pragma unroll
    for (int j = 0; j < 4; j++) {
        float s = ssum[j], q = ssq[j];
        #pragma unroll
        for (int o2 = 1; o2 < 16; o2 <<= 1) { s += __shfl_xor(s, o2); q += __shfl_xor(q, o2); }
        if (tx == 0) {
            atomicAdd(&stats_out[4 * ty + j], s);
            atomicAdd(&stats_out[64 + 4 * ty + j], q);
        }
    }
}

// --------------------------- edge: bn+relu -> lin(64->64) [+m_aggr scatter] + stats
// OUT-OF-PLACE: reads bf16 src, writes bf16 dst (different buffer). Staging via
// regular 8B loads + swizzled float4 ds_writes (R4-verified conflict-free LDS).

template<int AGGR>
__global__ __launch_bounds__(256) void k_edge_lin64(
    const float* __restrict__ stats_in, const float* __restrict__ gg,
    const float* __restrict__ be,
    const float* __restrict__ W, const float* __restrict__ B,
    const int* __restrict__ ei, float* __restrict__ magg,
    const u16* __restrict__ src, u16* __restrict__ dst,
    float* __restrict__ stats_out)
{
    __shared__ float Ws[64 * 64];
    __shared__ float As[64], Cs[64], Bs[64];
    __shared__ float in_t[64 * 64];
    int t = threadIdx.x;
    for (int i = t; i < 64 * 64; i += 256) Ws[i] = W[i];
    if (t < 64) {
        float mean = stats_in[t] * (1.f / Ee);
        float var  = stats_in[64 + t] * (1.f / Ee) - mean * mean;
        float a = gg[t] * rsqrtf(var + EPS);
        As[t] = a; Cs[t] = be[t] - mean * a; Bs[t] = B[t];
    }
    int tx = t & 15, ty = t >> 4;
    int srow = t >> 4;                      // staging row base (0..15)
    int sq   = t & 15;                      // staging channel quad
    int sqp  = 4 * (sq ^ srow);             // swizzled LDS quad position
    int nt = Ee / 64;
    float ssum[4] = {0, 0, 0, 0}, ssq[4] = {0, 0, 0, 0};

    for (int tile = blockIdx.x; tile < nt; tile += gridDim.x) {
        int te = tile * 64;
        // issue tile loads to registers (no LDS touch -> legal pre-barrier)
        ushort4 u0 = *(const ushort4*)&src[(size_t)(te + srow     ) * 64 + 4 * sq];
        ushort4 u1 = *(const ushort4*)&src[(size_t)(te + srow + 16) * 64 + 4 * sq];
        ushort4 u2 = *(const ushort4*)&src[(size_t)(te + srow + 32) * 64 + 4 * sq];
        ushort4 u3 = *(const ushort4*)&src[(size_t)(te + srow + 48) * 64 + 4 * sq];
        __syncthreads();                    // prev iteration's in_t reads done
        float4 f;
        f.x = bf2f(u0.x); f.y = bf2f(u0.y); f.z = bf2f(u0.z); f.w = bf2f(u0.w);
        *(float4*)&in_t[(srow     ) * 64 + sqp] = f;
        f.x = bf2f(u1.x); f.y = bf2f(u1.y); f.z = bf2f(u1.z); f.w = bf2f(u1.w);
        *(float4*)&in_t[(srow + 16) * 64 + sqp] = f;
        f.x = bf2f(u2.x); f.y = bf2f(u2.y); f.z = bf2f(u2.z); f.w = bf2f(u2.w);
        *(float4*)&in_t[(srow + 32) * 64 + sqp] = f;
        f.x = bf2f(u3.x); f.y = bf2f(u3.y); f.z = bf2f(u3.z); f.w = bf2f(u3.w);
        *(float4*)&in_t[(srow + 48) * 64 + sqp] = f;
        __syncthreads();                    // in_t ready

        float acc[4][4];
        {
            float4 b4 = *(const float4*)&Bs[4 * ty];
            #pragma unroll
            for (int i = 0; i < 4; i++) {
                acc[i][0] = b4.x; acc[i][1] = b4.y; acc[i][2] = b4.z; acc[i][3] = b4.w;
            }
        }
        #pragma unroll 4
        for (int kc = 0; kc < 16; kc++) {
            int p0 = 4 * (kc ^ tx);         // rows tx+16r: row&15 == tx
            float4 a0 = *(const float4*)&in_t[(tx     ) * 64 + p0];
            float4 a1 = *(const float4*)&in_t[(tx + 16) * 64 + p0];
            float4 a2 = *(const float4*)&in_t[(tx + 32) * 64 + p0];
            float4 a3 = *(const float4*)&in_t[(tx + 48) * 64 + p0];
            float4 as4 = *(const float4*)&As[4 * kc];
            float4 cs4 = *(const float4*)&Cs[4 * kc];
            BNRELU4(a0, as4, cs4); BNRELU4(a1, as4, cs4);
            BNRELU4(a2, as4, cs4); BNRELU4(a3, as4, cs4);
            float4 w0 = *(const float4*)&Ws[(4 * kc + 0) * 64 + 4 * ty];
            float4 w1 = *(const float4*)&Ws[(4 * kc + 1) * 64 + 4 * ty];
            float4 w2 = *(const float4*)&Ws[(4 * kc + 2) * 64 + 4 * ty];
            float4 w3 = *(const float4*)&Ws[(4 * kc + 3) * 64 + 4 * ty];
            FMAROW(acc[0], a0); FMAROW(acc[1], a1);
            FMAROW(acc[2], a2); FMAROW(acc[3], a3);
        }
        if (AGGR) {                         // scatter normalized m into magg[dst]
            int l = t & 63, w = t >> 6;
            int dnode = ei[Ee + te + l];
            #pragma unroll
            for (int q = 0; q < 4; q++) {
                int kq = 4 * q + w;
                float4 v = *(const float4*)&in_t[l * 64 + 4 * (kq ^ (l & 15))];
                float4 as4 = *(const float4*)&As[4 * kq];
                float4 cs4 = *(const float4*)&Cs[4 * kq];
                BNRELU4(v, as4, cs4);
                float* mg = &magg[(size_t)dnode * 64 + 4 * kq];
                atomicAdd(mg + 0, v.x); atomicAdd(mg + 1, v.y);
                atomicAdd(mg + 2, v.z); atomicAdd(mg + 3, v.w);
            }
        }
        #pragma unroll
        for (int i = 0; i < 4; i++) {
            ushort4 o;
            o.x = f2bf(acc[i][0]); o.y = f2bf(acc[i][1]);
            o.z = f2bf(acc[i][2]); o.w = f2bf(acc[i][3]);
            *(ushort4*)&dst[(size_t)(te + tx + 16 * i) * 64 + 4 * ty] = o;
            float r0 = bf2f(o.x), r1 = bf2f(o.y), r2 = bf2f(o.z), r3 = bf2f(o.w);
            ssum[0] += r0; ssum[1] += r1; ssum[2] += r2; ssum[3] += r3;
            ssq[0] += r0 * r0; ssq[1] += r1 * r1; ssq[2] += r2 * r2; ssq[3] += r3 * r3;
        }
    }
    #pragma unroll
    for (int j = 0; j < 4; j++) {
        float s = ssum[j], q = ssq[j];
        #pragma unroll
        for (int o2 = 1; o2 < 16; o2 <<= 1) { s += __shfl_xor(s, o2); q += __shfl_xor(q, o2); }
        if (tx == 0) {
            atomicAdd(&stats_out[4 * ty + j], s);
            atomicAdd(&stats_out[64 + 4 * ty + j], q);
        }
    }
}

// ------------------------------- edge: bn+relu -> pos_lin2 (64->1) -> scatter pos update

__global__ __launch_bounds__(256) void k_pos2(
    const float* __restrict__ stats_in, const float* __restrict__ gg, const float* __restrict__ be,
    const float* __restrict__ W2, const float* __restrict__ B2,
    const float* __restrict__ p, const int* __restrict__ ei,
    const u16* __restrict__ yb, float* __restrict__ pagg)
{
    __shared__ float As[64], Cs[64], Ws[64];
    int t = threadIdx.x;
    if (t < 64) {
        float mean = stats_in[t] * (1.f / Ee);
        float var  = stats_in[64 + t] * (1.f / Ee) - mean * mean;
        float a = gg[t] * rsqrtf(var + EPS);
        As[t] = a; Cs[t] = be[t] - mean * a; Ws[t] = W2[t];
    }
    __syncthreads();
    int e = blockIdx.x * 256 + t;
    const u16* row = &yb[(size_t)e * 64];
    float acc = B2[0];
    #pragma unroll 4
    for (int u = 0; u < 16; u++) {
        ushort4 y4 = *(const ushort4*)&row[4 * u];
        acc += fmaxf(As[4 * u + 0] * bf2f(y4.x) + Cs[4 * u + 0], 0.f) * Ws[4 * u + 0]
             + fmaxf(As[4 * u + 1] * bf2f(y4.y) + Cs[4 * u + 1], 0.f) * Ws[4 * u + 1]
             + fmaxf(As[4 * u + 2] * bf2f(y4.z) + Cs[4 * u + 2], 0.f) * Ws[4 * u + 2]
             + fmaxf(As[4 * u + 3] * bf2f(y4.w) + Cs[4 * u + 3], 0.f) * Ws[4 * u + 3];
    }
    int sr = ei[e], ds = ei[Ee + e];
    float dx = p[ds * 3 + 0] - p[sr * 3 + 0];
    float dy = p[ds * 3 + 1] - p[sr * 3 + 1];
    float dz = p[ds * 3 + 2] - p[sr * 3 + 2];
    atomicAdd(&pagg[ds * 3 + 0], dx * acc);
    atomicAdd(&pagg[ds * 3 + 1], dy * acc);
    atomicAdd(&pagg[ds * 3 + 2], dz * acc);
}

// ------------------------------------------- node: [h | m_aggr] (128 -> 64) + stats

__global__ __launch_bounds__(256) void k_node_lin1(
    const float* __restrict__ h, const float* __restrict__ magg,
    const float* __restrict__ W, const float* __restrict__ B,
    float* __restrict__ yn, float* __restrict__ stats_out)
{
    __shared__ float Ws[128 * 64];
    __shared__ float Bs[64];
    __shared__ float in_t[128 * ES];
    int t = threadIdx.x;
    for (int i = t; i < 128 * 64; i += 256) Ws[i] = W[i];
    if (t < 64) Bs[t] = B[t];
    int tx = t & 15, ty = t >> 4, c = t & 63, eg = t >> 6;
    float ssum[4] = {0, 0, 0, 0}, ssq[4] = {0, 0, 0, 0};
    int nT = (Nn + 63) / 64;
    for (int tile = blockIdx.x; tile < nT; tile += gridDim.x) {
        int te = tile * 64;
        __syncthreads();
        for (int e = eg; e < 64; e += 4) {
            int n = te + e;
            bool v = n < Nn;
            in_t[c * ES + e]        = v ? h[(size_t)n * 64 + c]    : 0.f;
            in_t[(64 + c) * ES + e] = v ? magg[(size_t)n * 64 + c] : 0.f;
        }
        __syncthreads();
        float acc[4][4];
        #pragma unroll
        for (int i = 0; i < 4; i++)
            #pragma unroll
            for (int j = 0; j < 4; j++) acc[i][j] = Bs[4 * ty + j];
        for (int k = 0; k < 128; k++) {
            float av[4], wv[4];
            *(float4*)av = *(const float4*)&in_t[k * ES + 4 * tx];
            *(float4*)wv = *(const float4*)&Ws[k * 64 + 4 * ty];
            #pragma unroll
            for (int i = 0; i < 4; i++)
                #pragma unroll
                for (int j = 0; j < 4; j++)
                    acc[i][j] += av[i] * wv[j];
        }
        #pragma unroll
        for (int i = 0; i < 4; i++) {
            int n = te + 4 * tx + i;
            if (n < Nn) {
                float4 o; o.x = acc[i][0]; o.y = acc[i][1]; o.z = acc[i][2]; o.w = acc[i][3];
                *(float4*)&yn[(size_t)n * 64 + 4 * ty] = o;
                #pragma unroll
                for (int j = 0; j < 4; j++) { ssum[j] += acc[i][j]; ssq[j] += acc[i][j] * acc[i][j]; }
            }
        }
    }
    #pragma unroll
    for (int j = 0; j < 4; j++) {
        float s = ssum[j], q = ssq[j];
        #pragma unroll
        for (int o2 = 1; o2 < 16; o2 <<= 1) { s += __shfl_xor(s, o2); q += __shfl_xor(q, o2); }
        if (tx == 0) {
            atomicAdd(&stats_out[4 * ty + j], s);
            atomicAdd(&stats_out[64 + 4 * ty + j], q);
        }
    }
}

// ------------------------------------------- node: bn+relu -> lin(64->64) + stats (in-place)

__global__ __launch_bounds__(256) void k_node_lin64(
    const float* __restrict__ stats_in, const float* __restrict__ gg, const float* __restrict__ be,
    const float* __restrict__ W, const float* __restrict__ B,
    float* __restrict__ yn, float* __restrict__ stats_out)
{
    __shared__ float Ws[64 * 64];
    __shared__ float As[64], Cs[64], Bs[64];
    __shared__ float in_t[64 * ES];
    int t = threadIdx.x;
    if (t < 64) {
        float mean = stats_in[t] * (1.f / Nn);
        float var  = stats_in[64 + t] * (1.f / Nn) - mean * mean;
        float a = gg[t] * rsqrtf(var + EPS);
        As[t] = a; Cs[t] = be[t] - mean * a; Bs[t] = B[t];
    }
    for (int i = t; i < 64 * 64; i += 256) Ws[i] = W[i];
    int tx = t & 15, ty = t >> 4, c = t & 63, eg = t >> 6;
    float ssum[4] = {0, 0, 0, 0}, ssq[4] = {0, 0, 0, 0};
    int nT = (Nn + 63) / 64;
    for (int tile = blockIdx.x; tile < nT; tile += gridDim.x) {
        int te = tile * 64;
        __syncthreads();
        for (int e = eg; e < 64; e += 4) {
            int n = te + e;
            float y = (n < Nn) ? yn[(size_t)n * 64 + c] : 0.f;
            in_t[c * ES + e] = fmaxf(As[c] * y + Cs[c], 0.f);
        }
        __syncthreads();
        float acc[4][4];
        #pragma unroll
        for (int i = 0; i < 4; i++)
            #pragma unroll
            for (int j = 0; j < 4; j++) acc[i][j] = Bs[4 * ty + j];
        for (int k = 0; k < 64; k++) {
            float av[4], wv[4];
            *(float4*)av = *(const float4*)&in_t[k * ES + 4 * tx];
            *(float4*)wv = *(const float4*)&Ws[k * 64 + 4 * ty];
            #pragma unroll
            for (int i = 0; i < 4; i++)
                #pragma unroll
                for (int j = 0; j < 4; j++)
                    acc[i][j] += av[i] * wv[j];
        }
        #pragma unroll
        for (int i = 0; i < 4; i++) {
            int n = te + 4 * tx + i;
            if (n < Nn) {
                float4 o; o.x = acc[i][0]; o.y = acc[i][1]; o.z = acc[i][2]; o.w = acc[i][3];
                *(float4*)&yn[(size_t)n * 64 + 4 * ty] = o;
                #pragma unroll
                for (int j = 0; j < 4; j++) { ssum[j] += acc[i][j]; ssq[j] += acc[i][j] * acc[i][j]; }
            }
        }
    }
    #pragma unroll
    for (int j = 0; j < 4; j++) {
        float s = ssum[j], q = ssq[j];
        #pragma unroll
        for (int o2 = 1; o2 < 16; o2 <<= 1) { s += __shfl_xor(s, o2); q += __shfl_xor(q, o2); }
        if (tx == 0) {
            atomicAdd(&stats_out[4 * ty + j], s);
            atomicAdd(&stats_out[64 + 4 * ty + j], q);
        }
    }
}

// ------------------------------------------- node: residual h += relu(bn(yn)); p update

__global__ __launch_bounds__(256) void k_node_update(
    const float* __restrict__ stats_in, const float* __restrict__ gg, const float* __restrict__ be,
    const float* __restrict__ yn, float* __restrict__ h,
    const float* __restrict__ p_in, float* __restrict__ p_out,
    const float* __restrict__ pagg, const float* __restrict__ deg)
{
    int i = blockIdx.x * 256 + threadIdx.x;
    if (i < Nn * 64) {
        int c = i & 63;
        float mean = stats_in[c] * (1.f / Nn);
        float var  = stats_in[64 + c] * (1.f / Nn) - mean * mean;
        float a = gg[c] * rsqrtf(var + EPS);
        float cc = be[c] - mean * a;
        h[i] += fmaxf(a * yn[i] + cc, 0.f);
    }
    if (i < Nn * 3) {
        float dg = fmaxf(deg[i / 3], 1.f);
        p_out[i] = p_in[i] + pagg[i] / dg;
    }
}

// ------------------------------------------- pooling + prediction head

__global__ __launch_bounds__(256) void k_pool(const int* __restrict__ batch,
    const float* __restrict__ h, float* __restrict__ pool)
{
    int i = blockIdx.x * 256 + threadIdx.x;
    if (i < Nn * 64) {
        int n = i >> 6, c = i & 63;
        atomicAdd(&pool[(size_t)batch[n] * 64 + c], h[i]);
    }
}

__global__ void k_out(const float* __restrict__ pool, const float* __restrict__ cnt,
    const float* __restrict__ W, const float* __restrict__ B, float* __restrict__ out)
{
    int g = threadIdx.x;
    if (g < 64) {
        float acc = 0.f;
        for (int c = 0; c < 64; c++) acc += pool[g * 64 + c] * W[c];
        out[g] = acc / fmaxf(cnt[g], 1.f) + B[0];
    }
}

// ---------------------------------------------------------------- launch

extern "C" void kernel_launch(void* const* d_in, const int* in_sizes, int n_in,
                              void* d_out, int out_size, void* d_ws, size_t ws_size,
                              hipStream_t stream)
{
    const float* x        = (const float*)d_in[0];
    const float* pos      = (const float*)d_in[1];
    const float* ea       = (const float*)d_in[2];
    const int*   ei       = (const int*)  d_in[3];
    const int*   batch    = (const int*)  d_in[4];
    const float* lin_in_w = (const float*)d_in[5];
    const float* lin_in_b = (const float*)d_in[6];
    const float* lin_pr_w = (const float*)d_in[7];
    const float* lin_pr_b = (const float*)d_in[8];
    const float* msg_w1   = (const float*)d_in[9];
    const float* msg_b1   = (const float*)d_in[10];
    const float* msg_g1   = (const float*)d_in[11];
    const float* msg_be1  = (const float*)d_in[12];
    const float* msg_w2   = (const float*)d_in[13];
    const float* msg_b2   = (const float*)d_in[14];
    const float* msg_g2   = (const float*)d_in[15];
    const float* msg_be2  = (const float*)d_in[16];
    const float* pos_w1   = (const float*)d_in[17];
    const float* pos_b1   = (const float*)d_in[18];
    const float* pos_g    = (const float*)d_in[19];
    const float* pos_be   = (const float*)d_in[20];
    const float* pos_w2   = (const float*)d_in[21];
    const float* pos_b2   = (const float*)d_in[22];
    const float* upd_w1   = (const float*)d_in[23];
    const float* upd_b1   = (const float*)d_in[24];
    const float* upd_g1   = (const float*)d_in[25];
    const float* upd_be1  = (const float*)d_in[26];
    const float* upd_w2   = (const float*)d_in[27];
    const float* upd_b2   = (const float*)d_in[28];
    const float* upd_g2   = (const float*)d_in[29];
    const float* upd_be2  = (const float*)d_in[30];
    float* out = (float*)d_out;

    float* ws = (float*)d_ws;
    size_t o = 0;
    float* h    = ws + o; o += (size_t)Nn * 64;
    u16*   ybA  = (u16*)(ws + o); o += (size_t)Ee * 64;  // two bf16 E*64 buffers
    u16*   ybB  = ybA + (size_t)Ee * 64;                 //   in the old fp32 footprint
    float* yn   = ws + o; o += (size_t)Nn * 64;
    float* magg = ws + o; o += (size_t)Nn * 64;   // magg + pagg contiguous (one memset)
    float* pagg = ws + o; o += (size_t)Nn * 3;
    float* pws  = ws + o; o += (size_t)Nn * 3;
    float* stats= ws + o; o += 1280;              // stats..deg contiguous (one memset)
    float* pool = ws + o; o += 64 * 64;
    float* cnt  = ws + o; o += 64;
    float* deg  = ws + o; o += Nn;
    if (ws_size < o * sizeof(float)) return;

    hipMemsetAsync(stats, 0, (size_t)(1280 + 64 * 64 + 64 + Nn) * sizeof(float), stream);
    k_lin_in<<<(Nn * 64 + 255) / 256, 256, 0, stream>>>(x, lin_in_w, lin_in_b, h);
    k_deg<<<(Ee + 255) / 256, 256, 0, stream>>>(ei, deg);
    k_cnt<<<(Nn + 255) / 256, 256, 0, stream>>>(batch, cnt);

    for (int l = 0; l < 2; l++) {
        hipMemsetAsync(magg, 0, ((size_t)Nn * 64 + (size_t)Nn * 3) * sizeof(float), stream);
        const float* pc = (l == 0) ? pos : pws;
        float* st = stats + (size_t)l * 5 * 128;
        k_edge_lin1<<<512, 256, 0, stream>>>(h, pc, ea, ei,
            msg_w1 + (size_t)l * KIN * 64, msg_b1 + l * 64, ybA, st + 0 * 128);
        k_edge_lin64<0><<<1024, 256, 0, stream>>>(st + 0 * 128, msg_g1 + l * 64, msg_be1 + l * 64,
            msg_w2 + (size_t)l * 64 * 64, msg_b2 + l * 64, ei, nullptr, ybA, ybB, st + 1 * 128);
        k_edge_lin64<1><<<1024, 256, 0, stream>>>(st + 1 * 128, msg_g2 + l * 64, msg_be2 + l * 64,
            pos_w1 + (size_t)l * 64 * 64, pos_b1 + l * 64, ei, magg, ybB, ybA, st + 2 * 128);
        k_pos2<<<Ee / 256, 256, 0, stream>>>(st + 2 * 128, pos_g + l * 64, pos_be + l * 64,
            pos_w2 + l * 64, pos_b2 + l, pc, ei, ybA, pagg);
        k_node_lin1<<<782, 256, 0, stream>>>(h, magg,
            upd_w1 + (size_t)l * 128 * 64, upd_b1 + l * 64, yn, st + 3 * 128);
        k_node_lin64<<<782, 256, 0, stream>>>(st + 3 * 128, upd_g1 + l * 64, upd_be1 + l * 64,
            upd_w2 + (size_t)l * 64 * 64, upd_b2 + l * 64, yn, st + 4 * 128);
        k_node_update<<<(Nn * 64 + 255) / 256, 256, 0, stream>>>(st + 4 * 128,
            upd_g2 + l * 64, upd_be2 + l * 64, yn, h, pc, pws, pagg, deg);
    }
    k_pool<<<(Nn * 64 + 255) / 256, 256, 0, stream>>>(batch, h, pool);
    k_out<<<1, 64, 0, stream>>>(pool, cnt, lin_pr_w, lin_pr_b, out);
}

// Round 7
// 2501.158 us; speedup vs baseline: 3.0908x; 3.0050x over previous
//
#include <hip/hip_runtime.h>

#define Nn 50000
#define Ee 800000
#define Gg 64
#define Dd 64
#define KIN 133      // 2*64 + 4 + 1
#define ES 68        // padded LDS tile stride (floats): 16B-aligned rows
#define EPS 1e-5f

// ---------------------------------------------------------------- helpers

__global__ __launch_bounds__(256) void k_lin_in(const float* __restrict__ x,
    const float* __restrict__ W, const float* __restrict__ B, float* __restrict__ h)
{
    __shared__ float Ws[11 * 64];
    __shared__ float Bs[64];
    int t = threadIdx.x;
    for (int i = t; i < 11 * 64; i += 256) Ws[i] = W[i];
    if (t < 64) Bs[t] = B[t];
    __syncthreads();
    int i = blockIdx.x * 256 + t;
    if (i < Nn * 64) {
        int n = i >> 6, c = i & 63;
        float acc = Bs[c];
        #pragma unroll
        for (int k = 0; k < 11; k++) acc += x[n * 11 + k] * Ws[k * 64 + c];
        h[i] = acc;
    }
}

__global__ __launch_bounds__(256) void k_deg(const int* __restrict__ ei, float* __restrict__ deg)
{
    int e = blockIdx.x * 256 + threadIdx.x;
    if (e < Ee) atomicAdd(&deg[ei[Ee + e]], 1.f);
}

__global__ __launch_bounds__(256) void k_cnt(const int* __restrict__ batch, float* __restrict__ cnt)
{
    int n = blockIdx.x * 256 + threadIdx.x;
    if (n < Nn) atomicAdd(&cnt[batch[n]], 1.f);
}

// ------------------------------------------------- edge lin1 (133 -> 64) + stats

__global__ __launch_bounds__(256) void k_edge_lin1(
    const float* __restrict__ h, const float* __restrict__ p,
    const float* __restrict__ ea, const int* __restrict__ ei,
    const float* __restrict__ W, const float* __restrict__ B,
    float* __restrict__ ybuf, float* __restrict__ stats_out)
{
    __shared__ float Ws[KIN * 64];
    __shared__ float Bs[64];
    __shared__ float in_t[KIN * ES];     // [k][e] transposed tile
    int t = threadIdx.x;
    for (int i = t; i < KIN * 64; i += 256) Ws[i] = W[i];
    if (t < 64) Bs[t] = B[t];
    int tx = t & 15, ty = t >> 4;        // compute: e0=4*tx, c0=4*ty
    int c = t & 63, eg = t >> 6;         // staging roles
    float ssum[4] = {0, 0, 0, 0}, ssq[4] = {0, 0, 0, 0};
    for (int tile = blockIdx.x; tile < Ee / 64; tile += gridDim.x) {
        int te = tile * 64;
        __syncthreads();
        for (int e = eg; e < 64; e += 4) {
            int sr = ei[te + e], ds = ei[Ee + te + e];
            in_t[c * ES + e]        = h[(size_t)ds * 64 + c];   // h_i = h[dst]
            in_t[(64 + c) * ES + e] = h[(size_t)sr * 64 + c];   // h_j = h[src]
        }
        if (t < 64) {
            int e = t;
            int sr = ei[te + e], ds = ei[Ee + te + e];
            float dx = p[ds * 3 + 0] - p[sr * 3 + 0];
            float dy = p[ds * 3 + 1] - p[sr * 3 + 1];
            float dz = p[ds * 3 + 2] - p[sr * 3 + 2];
            in_t[128 * ES + e] = dx * dx + dy * dy + dz * dz;
            float4 a4 = *(const float4*)&ea[(size_t)(te + e) * 4];
            in_t[129 * ES + e] = a4.x;
            in_t[130 * ES + e] = a4.y;
            in_t[131 * ES + e] = a4.z;
            in_t[132 * ES + e] = a4.w;
        }
        __syncthreads();
        float acc[4][4];
        #pragma unroll
        for (int i = 0; i < 4; i++)
            #pragma unroll
            for (int j = 0; j < 4; j++) acc[i][j] = Bs[4 * ty + j];
        for (int k = 0; k < KIN; k++) {
            float av[4], wv[4];
            *(float4*)av = *(const float4*)&in_t[k * ES + 4 * tx];
            *(float4*)wv = *(const float4*)&Ws[k * 64 + 4 * ty];
            #pragma unroll
            for (int i = 0; i < 4; i++)
                #pragma unroll
                for (int j = 0; j < 4; j++)
                    acc[i][j] += av[i] * wv[j];
        }
        #pragma unroll
        for (int i = 0; i < 4; i++) {
            size_t e = (size_t)te + 4 * tx + i;
            float4 o; o.x = acc[i][0]; o.y = acc[i][1]; o.z = acc[i][2]; o.w = acc[i][3];
            *(float4*)&ybuf[e * 64 + 4 * ty] = o;
            #pragma unroll
            for (int j = 0; j < 4; j++) { ssum[j] += acc[i][j]; ssq[j] += acc[i][j] * acc[i][j]; }
        }
    }
    #pragma unroll
    for (int j = 0; j < 4; j++) {
        float s = ssum[j], q = ssq[j];
        #pragma unroll
        for (int o2 = 1; o2 < 16; o2 <<= 1) { s += __shfl_xor(s, o2); q += __shfl_xor(q, o2); }
        if (tx == 0) {
            atomicAdd(&stats_out[4 * ty + j], s);
            atomicAdd(&stats_out[64 + 4 * ty + j], q);
        }
    }
}

// --------------------------- edge: bn+relu -> lin(64->64) [+optional m_aggr scatter] + stats

template<int AGGR>
__global__ __launch_bounds__(256) void k_edge_lin64(
    const float* __restrict__ stats_in, const float* __restrict__ gg,
    const float* __restrict__ be,
    const float* __restrict__ W, const float* __restrict__ B,
    const int* __restrict__ ei, float* __restrict__ magg,
    float* __restrict__ ybuf, float* __restrict__ stats_out)
{
    __shared__ float Ws[64 * 64];
    __shared__ float As[64], Cs[64], Bs[64];
    __shared__ float in_t[64 * ES];
    int t = threadIdx.x;
    if (t < 64) {
        float mean = stats_in[t] * (1.f / Ee);
        float var  = stats_in[64 + t] * (1.f / Ee) - mean * mean;
        float a = gg[t] * rsqrtf(var + EPS);
        As[t] = a; Cs[t] = be[t] - mean * a; Bs[t] = B[t];
    }
    for (int i = t; i < 64 * 64; i += 256) Ws[i] = W[i];
    int tx = t & 15, ty = t >> 4;
    int c = t & 63, eg = t >> 6;
    float ssum[4] = {0, 0, 0, 0}, ssq[4] = {0, 0, 0, 0};
    for (int tile = blockIdx.x; tile < Ee / 64; tile += gridDim.x) {
        int te = tile * 64;
        __syncthreads();
        for (int e = eg; e < 64; e += 4) {
            float y = ybuf[(size_t)(te + e) * 64 + c];
            in_t[c * ES + e] = fmaxf(As[c] * y + Cs[c], 0.f);
        }
        __syncthreads();
        float acc[4][4];
        #pragma unroll
        for (int i = 0; i < 4; i++)
            #pragma unroll
            for (int j = 0; j < 4; j++) acc[i][j] = Bs[4 * ty + j];
        for (int k = 0; k < 64; k++) {
            float av[4], wv[4];
            *(float4*)av = *(const float4*)&in_t[k * ES + 4 * tx];
            *(float4*)wv = *(const float4*)&Ws[k * 64 + 4 * ty];
            #pragma unroll
            for (int i = 0; i < 4; i++)
                #pragma unroll
                for (int j = 0; j < 4; j++)
                    acc[i][j] += av[i] * wv[j];
        }
        if (AGGR) {  // scatter-add the normalized input (= m) into m_aggr[dst]
            for (int e = eg; e < 64; e += 4) {
                int ds = ei[Ee + te + e];
                atomicAdd(&magg[(size_t)ds * 64 + c], in_t[c * ES + e]);
            }
        }
        #pragma unroll
        for (int i = 0; i < 4; i++) {
            size_t e = (size_t)te + 4 * tx + i;
            float4 o; o.x = acc[i][0]; o.y = acc[i][1]; o.z = acc[i][2]; o.w = acc[i][3];
            *(float4*)&ybuf[e * 64 + 4 * ty] = o;
            #pragma unroll
            for (int j = 0; j < 4; j++) { ssum[j] += acc[i][j]; ssq[j] += acc[i][j] * acc[i][j]; }
        }
    }
    #pragma unroll
    for (int j = 0; j < 4; j++) {
        float s = ssum[j], q = ssq[j];
        #pragma unroll
        for (int o2 = 1; o2 < 16; o2 <<= 1) { s += __shfl_xor(s, o2); q += __shfl_xor(q, o2); }
        if (tx == 0) {
            atomicAdd(&stats_out[4 * ty + j], s);
            atomicAdd(&stats_out[64 + 4 * ty + j], q);
        }
    }
}

// ------------------------------- edge: bn+relu -> pos_lin2 (64->1) -> scatter pos update

__global__ __launch_bounds__(256) void k_pos2(
    const float* __restrict__ stats_in, const float* __restrict__ gg, const float* __restrict__ be,
    const float* __restrict__ W2, const float* __restrict__ B2,
    const float* __restrict__ p, const int* __restrict__ ei,
    const float* __restrict__ ybuf, float* __restrict__ pagg)
{
    __shared__ float As[64], Cs[64], Ws[64];
    int t = threadIdx.x;
    if (t < 64) {
        float mean = stats_in[t] * (1.f / Ee);
        float var  = stats_in[64 + t] * (1.f / Ee) - mean * mean;
        float a = gg[t] * rsqrtf(var + EPS);
        As[t] = a; Cs[t] = be[t] - mean * a; Ws[t] = W2[t];
    }
    __syncthreads();
    int e = blockIdx.x * 256 + t;
    if (e >= Ee) return;
    float acc = B2[0];
    const float* row = &ybuf[(size_t)e * 64];
    #pragma unroll
    for (int u = 0; u < 16; u++) {
        float4 y = *(const float4*)&row[4 * u];
        acc += fmaxf(As[4 * u + 0] * y.x + Cs[4 * u + 0], 0.f) * Ws[4 * u + 0]
             + fmaxf(As[4 * u + 1] * y.y + Cs[4 * u + 1], 0.f) * Ws[4 * u + 1]
             + fmaxf(As[4 * u + 2] * y.z + Cs[4 * u + 2], 0.f) * Ws[4 * u + 2]
             + fmaxf(As[4 * u + 3] * y.w + Cs[4 * u + 3], 0.f) * Ws[4 * u + 3];
    }
    int sr = ei[e], ds = ei[Ee + e];
    float dx = p[ds * 3 + 0] - p[sr * 3 + 0];
    float dy = p[ds * 3 + 1] - p[sr * 3 + 1];
    float dz = p[ds * 3 + 2] - p[sr * 3 + 2];
    atomicAdd(&pagg[ds * 3 + 0], dx * acc);
    atomicAdd(&pagg[ds * 3 + 1], dy * acc);
    atomicAdd(&pagg[ds * 3 + 2], dz * acc);
}

// ------------------------------------------- node: [h | m_aggr] (128 -> 64) + stats

__global__ __launch_bounds__(256) void k_node_lin1(
    const float* __restrict__ h, const float* __restrict__ magg,
    const float* __restrict__ W, const float* __restrict__ B,
    float* __restrict__ yn, float* __restrict__ stats_out)
{
    __shared__ float Ws[128 * 64];
    __shared__ float Bs[64];
    __shared__ float in_t[128 * ES];
    int t = threadIdx.x;
    for (int i = t; i < 128 * 64; i += 256) Ws[i] = W[i];
    if (t < 64) Bs[t] = B[t];
    int tx = t & 15, ty = t >> 4, c = t & 63, eg = t >> 6;
    float ssum[4] = {0, 0, 0, 0}, ssq[4] = {0, 0, 0, 0};
    int nT = (Nn + 63) / 64;
    for (int tile = blockIdx.x; tile < nT; tile += gridDim.x) {
        int te = tile * 64;
        __syncthreads();
        for (int e = eg; e < 64; e += 4) {
            int n = te + e;
            bool v = n < Nn;
            in_t[c * ES + e]        = v ? h[(size_t)n * 64 + c]    : 0.f;
            in_t[(64 + c) * ES + e] = v ? magg[(size_t)n * 64 + c] : 0.f;
        }
        __syncthreads();
        float acc[4][4];
        #pragma unroll
        for (int i = 0; i < 4; i++)
            #pragma unroll
            for (int j = 0; j < 4; j++) acc[i][j] = Bs[4 * ty + j];
        for (int k = 0; k < 128; k++) {
            float av[4], wv[4];
            *(float4*)av = *(const float4*)&in_t[k * ES + 4 * tx];
            *(float4*)wv = *(const float4*)&Ws[k * 64 + 4 * ty];
            #pragma unroll
            for (int i = 0; i < 4; i++)
                #pragma unroll
                for (int j = 0; j < 4; j++)
                    acc[i][j] += av[i] * wv[j];
        }
        #pragma unroll
        for (int i = 0; i < 4; i++) {
            int n = te + 4 * tx + i;
            if (n < Nn) {
                float4 o; o.x = acc[i][0]; o.y = acc[i][1]; o.z = acc[i][2]; o.w = acc[i][3];
                *(float4*)&yn[(size_t)n * 64 + 4 * ty] = o;
                #pragma unroll
                for (int j = 0; j < 4; j++) { ssum[j] += acc[i][j]; ssq[j] += acc[i][j] * acc[i][j]; }
            }
        }
    }
    #pragma unroll
    for (int j = 0; j < 4; j++) {
        float s = ssum[j], q = ssq[j];
        #pragma unroll
        for (int o2 = 1; o2 < 16; o2 <<= 1) { s += __shfl_xor(s, o2); q += __shfl_xor(q, o2); }
        if (tx == 0) {
            atomicAdd(&stats_out[4 * ty + j], s);
            atomicAdd(&stats_out[64 + 4 * ty + j], q);
        }
    }
}

// ------------------------------------------- node: bn+relu -> lin(64->64) + stats (in-place)

__global__ __launch_bounds__(256) void k_node_lin64(
    const float* __restrict__ stats_in, const float* __restrict__ gg, const float* __restrict__ be,
    const float* __restrict__ W, const float* __restrict__ B,
    float* __restrict__ yn, float* __restrict__ stats_out)
{
    __shared__ float Ws[64 * 64];
    __shared__ float As[64], Cs[64], Bs[64];
    __shared__ float in_t[64 * ES];
    int t = threadIdx.x;
    if (t < 64) {
        float mean = stats_in[t] * (1.f / Nn);
        float var  = stats_in[64 + t] * (1.f / Nn) - mean * mean;
        float a = gg[t] * rsqrtf(var + EPS);
        As[t] = a; Cs[t] = be[t] - mean * a; Bs[t] = B[t];
    }
    for (int i = t; i < 64 * 64; i += 256) Ws[i] = W[i];
    int tx = t & 15, ty = t >> 4, c = t & 63, eg = t >> 6;
    float ssum[4] = {0, 0, 0, 0}, ssq[4] = {0, 0, 0, 0};
    int nT = (Nn + 63) / 64;
    for (int tile = blockIdx.x; tile < nT; tile += gridDim.x) {
        int te = tile * 64;
        __syncthreads();
        for (int e = eg; e < 64; e += 4) {
            int n = te + e;
            float y = (n < Nn) ? yn[(size_t)n * 64 + c] : 0.f;
            in_t[c * ES + e] = fmaxf(As[c] * y + Cs[c], 0.f);
        }
        __syncthreads();
        float acc[4][4];
        #pragma unroll
        for (int i = 0; i < 4; i++)
            #pragma unroll
            for (int j = 0; j < 4; j++) acc[i][j] = Bs[4 * ty + j];
        for (int k = 0; k < 64; k++) {
            float av[4], wv[4];
            *(float4*)av = *(const float4*)&in_t[k * ES + 4 * tx];
            *(float4*)wv = *(const float4*)&Ws[k * 64 + 4 * ty];
            #pragma unroll
            for (int i = 0; i < 4; i++)
                #pragma unroll
                for (int j = 0; j < 4; j++)
                    acc[i][j] += av[i] * wv[j];
        }
        #pragma unroll
        for (int i = 0; i < 4; i++) {
            int n = te + 4 * tx + i;
            if (n < Nn) {
                float4 o; o.x = acc[i][0]; o.y = acc[i][1]; o.z = acc[i][2]; o.w = acc[i][3];
                *(float4*)&yn[(size_t)n * 64 + 4 * ty] = o;
                #pragma unroll
                for (int j = 0; j < 4; j++) { ssum[j] += acc[i][j]; ssq[j] += acc[i][j] * acc[i][j]; }
            }
        }
    }
    #pragma unroll
    for (int j = 0; j < 4; j++) {
        float s = ssum[j], q = ssq[j];
        #pragma unroll
        for (int o2 = 1; o2 < 16; o2 <<= 1) { s += __shfl_xor(s, o2); q += __shfl_xor(q, o2); }
        if (tx == 0) {
            atomicAdd(&stats_out[4 * ty + j], s);
            atomicAdd(&stats_out[64 + 4 * ty + j], q);
        }
    }
}

// ------------------------------------------- node: residual h += relu(bn(yn)); p update

__global__ __launch_bounds__(256) void k_node_update(
    const float* __restrict__ stats_in, const float* __restrict__ gg, const float* __restrict__ be,
    const float* __restrict__ yn, float* __restrict__ h,
    const float* __restrict__ p_in, float* __restrict__ p_out,
    const float* __restrict__ pagg, const float* __restrict__ deg)
{
    int i = blockIdx.x * 256 + threadIdx.x;
    if (i < Nn * 64) {
        int c = i & 63;
        float mean = stats_in[c] * (1.f / Nn);
        float var  = stats_in[64 + c] * (1.f / Nn) - mean * mean;
        float a = gg[c] * rsqrtf(var + EPS);
        float cc = be[c] - mean * a;
        h[i] += fmaxf(a * yn[i] + cc, 0.f);
    }
    if (i < Nn * 3) {
        float dg = fmaxf(deg[i / 3], 1.f);
        p_out[i] = p_in[i] + pagg[i] / dg;
    }
}

// ------------------------------------------- pooling + prediction head

__global__ __launch_bounds__(256) void k_pool(const int* __restrict__ batch,
    const float* __restrict__ h, float* __restrict__ pool)
{
    int i = blockIdx.x * 256 + threadIdx.x;
    if (i < Nn * 64) {
        int n = i >> 6, c = i & 63;
        atomicAdd(&pool[(size_t)batch[n] * 64 + c], h[i]);
    }
}

__global__ void k_out(const float* __restrict__ pool, const float* __restrict__ cnt,
    const float* __restrict__ W, const float* __restrict__ B, float* __restrict__ out)
{
    int g = threadIdx.x;
    if (g < 64) {
        float acc = 0.f;
        for (int c = 0; c < 64; c++) acc += pool[g * 64 + c] * W[c];
        out[g] = acc / fmaxf(cnt[g], 1.f) + B[0];
    }
}

// ---------------------------------------------------------------- launch

extern "C" void kernel_launch(void* const* d_in, const int* in_sizes, int n_in,
                              void* d_out, int out_size, void* d_ws, size_t ws_size,
                              hipStream_t stream)
{
    const float* x        = (const float*)d_in[0];
    const float* pos      = (const float*)d_in[1];
    const float* ea       = (const float*)d_in[2];
    const int*   ei       = (const int*)  d_in[3];
    const int*   batch    = (const int*)  d_in[4];
    const float* lin_in_w = (const float*)d_in[5];
    const float* lin_in_b = (const float*)d_in[6];
    const float* lin_pr_w = (const float*)d_in[7];
    const float* lin_pr_b = (const float*)d_in[8];
    const float* msg_w1   = (const float*)d_in[9];
    const float* msg_b1   = (const float*)d_in[10];
    const float* msg_g1   = (const float*)d_in[11];
    const float* msg_be1  = (const float*)d_in[12];
    const float* msg_w2   = (const float*)d_in[13];
    const float* msg_b2   = (const float*)d_in[14];
    const float* msg_g2   = (const float*)d_in[15];
    const float* msg_be2  = (const float*)d_in[16];
    const float* pos_w1   = (const float*)d_in[17];
    const float* pos_b1   = (const float*)d_in[18];
    const float* pos_g    = (const float*)d_in[19];
    const float* pos_be   = (const float*)d_in[20];
    const float* pos_w2   = (const float*)d_in[21];
    const float* pos_b2   = (const float*)d_in[22];
    const float* upd_w1   = (const float*)d_in[23];
    const float* upd_b1   = (const float*)d_in[24];
    const float* upd_g1   = (const float*)d_in[25];
    const float* upd_be1  = (const float*)d_in[26];
    const float* upd_w2   = (const float*)d_in[27];
    const float* upd_b2   = (const float*)d_in[28];
    const float* upd_g2   = (const float*)d_in[29];
    const float* upd_be2  = (const float*)d_in[30];
    float* out = (float*)d_out;

    float* ws = (float*)d_ws;
    size_t o = 0;
    float* h    = ws + o; o += (size_t)Nn * 64;
    float* ybuf = ws + o; o += (size_t)Ee * 64;
    float* yn   = ws + o; o += (size_t)Nn * 64;
    float* magg = ws + o; o += (size_t)Nn * 64;   // magg + pagg contiguous (one memset)
    float* pagg = ws + o; o += (size_t)Nn * 3;
    float* pws  = ws + o; o += (size_t)Nn * 3;
    float* stats= ws + o; o += 1280;              // stats..deg contiguous (one memset)
    float* pool = ws + o; o += 64 * 64;
    float* cnt  = ws + o; o += 64;
    float* deg  = ws + o; o += Nn;
    if (ws_size < o * sizeof(float)) return;

    hipMemsetAsync(stats, 0, (size_t)(1280 + 64 * 64 + 64 + Nn) * sizeof(float), stream);
    k_lin_in<<<(Nn * 64 + 255) / 256, 256, 0, stream>>>(x, lin_in_w, lin_in_b, h);
    k_deg<<<(Ee + 255) / 256, 256, 0, stream>>>(ei, deg);
    k_cnt<<<(Nn + 255) / 256, 256, 0, stream>>>(batch, cnt);

    for (int l = 0; l < 2; l++) {
        hipMemsetAsync(magg, 0, ((size_t)Nn * 64 + (size_t)Nn * 3) * sizeof(float), stream);
        const float* pc = (l == 0) ? pos : pws;
        float* st = stats + (size_t)l * 5 * 128;
        k_edge_lin1<<<512, 256, 0, stream>>>(h, pc, ea, ei,
            msg_w1 + (size_t)l * KIN * 64, msg_b1 + l * 64, ybuf, st + 0 * 128);
        k_edge_lin64<0><<<1024, 256, 0, stream>>>(st + 0 * 128, msg_g1 + l * 64, msg_be1 + l * 64,
            msg_w2 + (size_t)l * 64 * 64, msg_b2 + l * 64, ei, nullptr, ybuf, st + 1 * 128);
        k_edge_lin64<1><<<1024, 256, 0, stream>>>(st + 1 * 128, msg_g2 + l * 64, msg_be2 + l * 64,
            pos_w1 + (size_t)l * 64 * 64, pos_b1 + l * 64, ei, magg, ybuf, st + 2 * 128);
        k_pos2<<<(Ee + 255) / 256, 256, 0, stream>>>(st + 2 * 128, pos_g + l * 64, pos_be + l * 64,
            pos_w2 + l * 64, pos_b2 + l, pc, ei, ybuf, pagg);
        k_node_lin1<<<782, 256, 0, stream>>>(h, magg,
            upd_w1 + (size_t)l * 128 * 64, upd_b1 + l * 64, yn, st + 3 * 128);
        k_node_lin64<<<782, 256, 0, stream>>>(st + 3 * 128, upd_g1 + l * 64, upd_be1 + l * 64,
            upd_w2 + (size_t)l * 64 * 64, upd_b2 + l * 64, yn, st + 4 * 128);
        k_node_update<<<(Nn * 64 + 255) / 256, 256, 0, stream>>>(st + 4 * 128,
            upd_g2 + l * 64, upd_be2 + l * 64, yn, h, pc, pws, pagg, deg);
    }
    k_pool<<<(Nn * 64 + 255) / 256, 256, 0, stream>>>(batch, h, pool);
    k_out<<<1, 64, 0, stream>>>(pool, cnt, lin_pr_w, lin_pr_b, out);
}

// Round 8
// 2475.959 us; speedup vs baseline: 3.1223x; 1.0102x over previous
//
#include <hip/hip_runtime.h>

#define Nn 50000
#define Ee 800000
#define Gg 64
#define Dd 64
#define KIN 133      // 2*64 + 4 + 1
#define ES 68        // padded LDS tile stride (floats): 16B-aligned rows
#define EPS 1e-5f

typedef unsigned short u16;

// bf16 round-to-nearest-even pack/unpack
__device__ __forceinline__ u16 f2bf(float f) {
    union { float f; unsigned u; } v; v.f = f;
    unsigned r = (v.u + 0x7FFFu + ((v.u >> 16) & 1u)) >> 16;
    return (u16)r;
}
__device__ __forceinline__ float bf2f(u16 s) {
    union { unsigned u; float f; } v; v.u = ((unsigned)s) << 16;
    return v.f;
}

// ---------------------------------------------------------------- helpers

__global__ __launch_bounds__(256) void k_lin_in(const float* __restrict__ x,
    const float* __restrict__ W, const float* __restrict__ B, float* __restrict__ h)
{
    __shared__ float Ws[11 * 64];
    __shared__ float Bs[64];
    int t = threadIdx.x;
    for (int i = t; i < 11 * 64; i += 256) Ws[i] = W[i];
    if (t < 64) Bs[t] = B[t];
    __syncthreads();
    int i = blockIdx.x * 256 + t;
    if (i < Nn * 64) {
        int n = i >> 6, c = i & 63;
        float acc = Bs[c];
        #pragma unroll
        for (int k = 0; k < 11; k++) acc += x[n * 11 + k] * Ws[k * 64 + c];
        h[i] = acc;
    }
}

__global__ __launch_bounds__(256) void k_deg(const int* __restrict__ ei, float* __restrict__ deg)
{
    int e = blockIdx.x * 256 + threadIdx.x;
    if (e < Ee) atomicAdd(&deg[ei[Ee + e]], 1.f);
}

__global__ __launch_bounds__(256) void k_cnt(const int* __restrict__ batch, float* __restrict__ cnt)
{
    int n = blockIdx.x * 256 + threadIdx.x;
    if (n < Nn) atomicAdd(&cnt[batch[n]], 1.f);
}

// ------------------------------------------------- edge lin1 (133 -> 64) + stats
// R1-exact structure; output stored bf16 (stats from rounded values).

__global__ __launch_bounds__(256) void k_edge_lin1(
    const float* __restrict__ h, const float* __restrict__ p,
    const float* __restrict__ ea, const int* __restrict__ ei,
    const float* __restrict__ W, const float* __restrict__ B,
    u16* __restrict__ ybuf, float* __restrict__ stats_out)
{
    __shared__ float Ws[KIN * 64];
    __shared__ float Bs[64];
    __shared__ float in_t[KIN * ES];     // [k][e] transposed tile
    int t = threadIdx.x;
    for (int i = t; i < KIN * 64; i += 256) Ws[i] = W[i];
    if (t < 64) Bs[t] = B[t];
    int tx = t & 15, ty = t >> 4;        // compute: e0=4*tx, c0=4*ty
    int c = t & 63, eg = t >> 6;         // staging roles
    float ssum[4] = {0, 0, 0, 0}, ssq[4] = {0, 0, 0, 0};
    for (int tile = blockIdx.x; tile < Ee / 64; tile += gridDim.x) {
        int te = tile * 64;
        __syncthreads();
        for (int e = eg; e < 64; e += 4) {
            int sr = ei[te + e], ds = ei[Ee + te + e];
            in_t[c * ES + e]        = h[(size_t)ds * 64 + c];   // h_i = h[dst]
            in_t[(64 + c) * ES + e] = h[(size_t)sr * 64 + c];   // h_j = h[src]
        }
        if (t < 64) {
            int e = t;
            int sr = ei[te + e], ds = ei[Ee + te + e];
            float dx = p[ds * 3 + 0] - p[sr * 3 + 0];
            float dy = p[ds * 3 + 1] - p[sr * 3 + 1];
            float dz = p[ds * 3 + 2] - p[sr * 3 + 2];
            in_t[128 * ES + e] = dx * dx + dy * dy + dz * dz;
            float4 a4 = *(const float4*)&ea[(size_t)(te + e) * 4];
            in_t[129 * ES + e] = a4.x;
            in_t[130 * ES + e] = a4.y;
            in_t[131 * ES + e] = a4.z;
            in_t[132 * ES + e] = a4.w;
        }
        __syncthreads();
        float acc[4][4];
        #pragma unroll
        for (int i = 0; i < 4; i++)
            #pragma unroll
            for (int j = 0; j < 4; j++) acc[i][j] = Bs[4 * ty + j];
        for (int k = 0; k < KIN; k++) {
            float av[4], wv[4];
            *(float4*)av = *(const float4*)&in_t[k * ES + 4 * tx];
            *(float4*)wv = *(const float4*)&Ws[k * 64 + 4 * ty];
            #pragma unroll
            for (int i = 0; i < 4; i++)
                #pragma unroll
                for (int j = 0; j < 4; j++)
                    acc[i][j] += av[i] * wv[j];
        }
        #pragma unroll
        for (int i = 0; i < 4; i++) {
            size_t e = (size_t)te + 4 * tx + i;
            ushort4 o;
            o.x = f2bf(acc[i][0]); o.y = f2bf(acc[i][1]);
            o.z = f2bf(acc[i][2]); o.w = f2bf(acc[i][3]);
            *(ushort4*)&ybuf[e * 64 + 4 * ty] = o;
            float r0 = bf2f(o.x), r1 = bf2f(o.y), r2 = bf2f(o.z), r3 = bf2f(o.w);
            ssum[0] += r0; ssum[1] += r1; ssum[2] += r2; ssum[3] += r3;
            ssq[0] += r0 * r0; ssq[1] += r1 * r1; ssq[2] += r2 * r2; ssq[3] += r3 * r3;
        }
    }
    #pragma unroll
    for (int j = 0; j < 4; j++) {
        float s = ssum[j], q = ssq[j];
        #pragma unroll
        for (int o2 = 1; o2 < 16; o2 <<= 1) { s += __shfl_xor(s, o2); q += __shfl_xor(q, o2); }
        if (tx == 0) {
            atomicAdd(&stats_out[4 * ty + j], s);
            atomicAdd(&stats_out[64 + 4 * ty + j], q);
        }
    }
}

// --------------------------- edge: bn+relu -> lin(64->64) [+optional m_aggr scatter] + stats
// R1-exact structure; ybuf is bf16, in-place.

template<int AGGR>
__global__ __launch_bounds__(256) void k_edge_lin64(
    const float* __restrict__ stats_in, const float* __restrict__ gg,
    const float* __restrict__ be,
    const float* __restrict__ W, const float* __restrict__ B,
    const int* __restrict__ ei, float* __restrict__ magg,
    u16* __restrict__ ybuf, float* __restrict__ stats_out)
{
    __shared__ float Ws[64 * 64];
    __shared__ float As[64], Cs[64], Bs[64];
    __shared__ float in_t[64 * ES];
    int t = threadIdx.x;
    if (t < 64) {
        float mean = stats_in[t] * (1.f / Ee);
        float var  = stats_in[64 + t] * (1.f / Ee) - mean * mean;
        float a = gg[t] * rsqrtf(var + EPS);
        As[t] = a; Cs[t] = be[t] - mean * a; Bs[t] = B[t];
    }
    for (int i = t; i < 64 * 64; i += 256) Ws[i] = W[i];
    int tx = t & 15, ty = t >> 4;
    int c = t & 63, eg = t >> 6;
    float ssum[4] = {0, 0, 0, 0}, ssq[4] = {0, 0, 0, 0};
    for (int tile = blockIdx.x; tile < Ee / 64; tile += gridDim.x) {
        int te = tile * 64;
        __syncthreads();
        for (int e = eg; e < 64; e += 4) {
            float y = bf2f(ybuf[(size_t)(te + e) * 64 + c]);
            in_t[c * ES + e] = fmaxf(As[c] * y + Cs[c], 0.f);
        }
        __syncthreads();
        float acc[4][4];
        #pragma unroll
        for (int i = 0; i < 4; i++)
            #pragma unroll
            for (int j = 0; j < 4; j++) acc[i][j] = Bs[4 * ty + j];
        for (int k = 0; k < 64; k++) {
            float av[4], wv[4];
            *(float4*)av = *(const float4*)&in_t[k * ES + 4 * tx];
            *(float4*)wv = *(const float4*)&Ws[k * 64 + 4 * ty];
            #pragma unroll
            for (int i = 0; i < 4; i++)
                #pragma unroll
                for (int j = 0; j < 4; j++)
                    acc[i][j] += av[i] * wv[j];
        }
        if (AGGR) {  // scatter-add the normalized input (= m) into m_aggr[dst]
            for (int e = eg; e < 64; e += 4) {
                int ds = ei[Ee + te + e];
                atomicAdd(&magg[(size_t)ds * 64 + c], in_t[c * ES + e]);
            }
        }
        #pragma unroll
        for (int i = 0; i < 4; i++) {
            size_t e = (size_t)te + 4 * tx + i;
            ushort4 o;
            o.x = f2bf(acc[i][0]); o.y = f2bf(acc[i][1]);
            o.z = f2bf(acc[i][2]); o.w = f2bf(acc[i][3]);
            *(ushort4*)&ybuf[e * 64 + 4 * ty] = o;
            float r0 = bf2f(o.x), r1 = bf2f(o.y), r2 = bf2f(o.z), r3 = bf2f(o.w);
            ssum[0] += r0; ssum[1] += r1; ssum[2] += r2; ssum[3] += r3;
            ssq[0] += r0 * r0; ssq[1] += r1 * r1; ssq[2] += r2 * r2; ssq[3] += r3 * r3;
        }
    }
    #pragma unroll
    for (int j = 0; j < 4; j++) {
        float s = ssum[j], q = ssq[j];
        #pragma unroll
        for (int o2 = 1; o2 < 16; o2 <<= 1) { s += __shfl_xor(s, o2); q += __shfl_xor(q, o2); }
        if (tx == 0) {
            atomicAdd(&stats_out[4 * ty + j], s);
            atomicAdd(&stats_out[64 + 4 * ty + j], q);
        }
    }
}

// ------------------------------- edge: bn+relu -> pos_lin2 (64->1) -> scatter pos update

__global__ __launch_bounds__(256) void k_pos2(
    const float* __restrict__ stats_in, const float* __restrict__ gg, const float* __restrict__ be,
    const float* __restrict__ W2, const float* __restrict__ B2,
    const float* __restrict__ p, const int* __restrict__ ei,
    const u16* __restrict__ ybuf, float* __restrict__ pagg)
{
    __shared__ float As[64], Cs[64], Ws[64];
    int t = threadIdx.x;
    if (t < 64) {
        float mean = stats_in[t] * (1.f / Ee);
        float var  = stats_in[64 + t] * (1.f / Ee) - mean * mean;
        float a = gg[t] * rsqrtf(var + EPS);
        As[t] = a; Cs[t] = be[t] - mean * a; Ws[t] = W2[t];
    }
    __syncthreads();
    int e = blockIdx.x * 256 + t;
    if (e >= Ee) return;
    float acc = B2[0];
    const u16* row = &ybuf[(size_t)e * 64];
    #pragma unroll
    for (int u = 0; u < 16; u++) {
        ushort4 y4 = *(const ushort4*)&row[4 * u];
        acc += fmaxf(As[4 * u + 0] * bf2f(y4.x) + Cs[4 * u + 0], 0.f) * Ws[4 * u + 0]
             + fmaxf(As[4 * u + 1] * bf2f(y4.y) + Cs[4 * u + 1], 0.f) * Ws[4 * u + 1]
             + fmaxf(As[4 * u + 2] * bf2f(y4.z) + Cs[4 * u + 2], 0.f) * Ws[4 * u + 2]
             + fmaxf(As[4 * u + 3] * bf2f(y4.w) + Cs[4 * u + 3], 0.f) * Ws[4 * u + 3];
    }
    int sr = ei[e], ds = ei[Ee + e];
    float dx = p[ds * 3 + 0] - p[sr * 3 + 0];
    float dy = p[ds * 3 + 1] - p[sr * 3 + 1];
    float dz = p[ds * 3 + 2] - p[sr * 3 + 2];
    atomicAdd(&pagg[ds * 3 + 0], dx * acc);
    atomicAdd(&pagg[ds * 3 + 1], dy * acc);
    atomicAdd(&pagg[ds * 3 + 2], dz * acc);
}

// ------------------------------------------- node: [h | m_aggr] (128 -> 64) + stats

__global__ __launch_bounds__(256) void k_node_lin1(
    const float* __restrict__ h, const float* __restrict__ magg,
    const float* __restrict__ W, const float* __restrict__ B,
    float* __restrict__ yn, float* __restrict__ stats_out)
{
    __shared__ float Ws[128 * 64];
    __shared__ float Bs[64];
    __shared__ float in_t[128 * ES];
    int t = threadIdx.x;
    for (int i = t; i < 128 * 64; i += 256) Ws[i] = W[i];
    if (t < 64) Bs[t] = B[t];
    int tx = t & 15, ty = t >> 4, c = t & 63, eg = t >> 6;
    float ssum[4] = {0, 0, 0, 0}, ssq[4] = {0, 0, 0, 0};
    int nT = (Nn + 63) / 64;
    for (int tile = blockIdx.x; tile < nT; tile += gridDim.x) {
        int te = tile * 64;
        __syncthreads();
        for (int e = eg; e < 64; e += 4) {
            int n = te + e;
            bool v = n < Nn;
            in_t[c * ES + e]        = v ? h[(size_t)n * 64 + c]    : 0.f;
            in_t[(64 + c) * ES + e] = v ? magg[(size_t)n * 64 + c] : 0.f;
        }
        __syncthreads();
        float acc[4][4];
        #pragma unroll
        for (int i = 0; i < 4; i++)
            #pragma unroll
            for (int j = 0; j < 4; j++) acc[i][j] = Bs[4 * ty + j];
        for (int k = 0; k < 128; k++) {
            float av[4], wv[4];
            *(float4*)av = *(const float4*)&in_t[k * ES + 4 * tx];
            *(float4*)wv = *(const float4*)&Ws[k * 64 + 4 * ty];
            #pragma unroll
            for (int i = 0; i < 4; i++)
                #pragma unroll
                for (int j = 0; j < 4; j++)
                    acc[i][j] += av[i] * wv[j];
        }
        #pragma unroll
        for (int i = 0; i < 4; i++) {
            int n = te + 4 * tx + i;
            if (n < Nn) {
                float4 o; o.x = acc[i][0]; o.y = acc[i][1]; o.z = acc[i][2]; o.w = acc[i][3];
                *(float4*)&yn[(size_t)n * 64 + 4 * ty] = o;
                #pragma unroll
                for (int j = 0; j < 4; j++) { ssum[j] += acc[i][j]; ssq[j] += acc[i][j] * acc[i][j]; }
            }
        }
    }
    #pragma unroll
    for (int j = 0; j < 4; j++) {
        float s = ssum[j], q = ssq[j];
        #pragma unroll
        for (int o2 = 1; o2 < 16; o2 <<= 1) { s += __shfl_xor(s, o2); q += __shfl_xor(q, o2); }
        if (tx == 0) {
            atomicAdd(&stats_out[4 * ty + j], s);
            atomicAdd(&stats_out[64 + 4 * ty + j], q);
        }
    }
}

// ------------------------------------------- node: bn+relu -> lin(64->64) + stats (in-place)

__global__ __launch_bounds__(256) void k_node_lin64(
    const float* __restrict__ stats_in, const float* __restrict__ gg, const float* __restrict__ be,
    const float* __restrict__ W, const float* __restrict__ B,
    float* __restrict__ yn, float* __restrict__ stats_out)
{
    __shared__ float Ws[64 * 64];
    __shared__ float As[64], Cs[64], Bs[64];
    __shared__ float in_t[64 * ES];
    int t = threadIdx.x;
    if (t < 64) {
        float mean = stats_in[t] * (1.f / Nn);
        float var  = stats_in[64 + t] * (1.f / Nn) - mean * mean;
        float a = gg[t] * rsqrtf(var + EPS);
        As[t] = a; Cs[t] = be[t] - mean * a; Bs[t] = B[t];
    }
    for (int i = t; i < 64 * 64; i += 256) Ws[i] = W[i];
    int tx = t & 15, ty = t >> 4, c = t & 63, eg = t >> 6;
    float ssum[4] = {0, 0, 0, 0}, ssq[4] = {0, 0, 0, 0};
    int nT = (Nn + 63) / 64;
    for (int tile = blockIdx.x; tile < nT; tile += gridDim.x) {
        int te = tile * 64;
        __syncthreads();
        for (int e = eg; e < 64; e += 4) {
            int n = te + e;
            float y = (n < Nn) ? yn[(size_t)n * 64 + c] : 0.f;
            in_t[c * ES + e] = fmaxf(As[c] * y + Cs[c], 0.f);
        }
        __syncthreads();
        float acc[4][4];
        #pragma unroll
        for (int i = 0; i < 4; i++)
            #pragma unroll
            for (int j = 0; j < 4; j++) acc[i][j] = Bs[4 * ty + j];
        for (int k = 0; k < 64; k++) {
            float av[4], wv[4];
            *(float4*)av = *(const float4*)&in_t[k * ES + 4 * tx];
            *(float4*)wv = *(const float4*)&Ws[k * 64 + 4 * ty];
            #pragma unroll
            for (int i = 0; i < 4; i++)
                #pragma unroll
                for (int j = 0; j < 4; j++)
                    acc[i][j] += av[i] * wv[j];
        }
        #pragma unroll
        for (int i = 0; i < 4; i++) {
            int n = te + 4 * tx + i;
            if (n < Nn) {
                float4 o; o.x = acc[i][0]; o.y = acc[i][1]; o.z = acc[i][2]; o.w = acc[i][3];
                *(float4*)&yn[(size_t)n * 64 + 4 * ty] = o;
                #pragma unroll
                for (int j = 0; j < 4; j++) { ssum[j] += acc[i][j]; ssq[j] += acc[i][j] * acc[i][j]; }
            }
        }
    }
    #pragma unroll
    for (int j = 0; j < 4; j++) {
        float s = ssum[j], q = ssq[j];
        #pragma unroll
        for (int o2 = 1; o2 < 16; o2 <<= 1) { s += __shfl_xor(s, o2); q += __shfl_xor(q, o2); }
        if (tx == 0) {
            atomicAdd(&stats_out[4 * ty + j], s);
            atomicAdd(&stats_out[64 + 4 * ty + j], q);
        }
    }
}

// ------------------------------------------- node: residual h += relu(bn(yn)); p update

__global__ __launch_bounds__(256) void k_node_update(
    const float* __restrict__ stats_in, const float* __restrict__ gg, const float* __restrict__ be,
    const float* __restrict__ yn, float* __restrict__ h,
    const float* __restrict__ p_in, float* __restrict__ p_out,
    const float* __restrict__ pagg, const float* __restrict__ deg)
{
    int i = blockIdx.x * 256 + threadIdx.x;
    if (i < Nn * 64) {
        int c = i & 63;
        float mean = stats_in[c] * (1.f / Nn);
        float var  = stats_in[64 + c] * (1.f / Nn) - mean * mean;
        float a = gg[c] * rsqrtf(var + EPS);
        float cc = be[c] - mean * a;
        h[i] += fmaxf(a * yn[i] + cc, 0.f);
    }
    if (i < Nn * 3) {
        float dg = fmaxf(deg[i / 3], 1.f);
        p_out[i] = p_in[i] + pagg[i] / dg;
    }
}

// ------------------------------------------- pooling + prediction head

__global__ __launch_bounds__(256) void k_pool(const int* __restrict__ batch,
    const float* __restrict__ h, float* __restrict__ pool)
{
    int i = blockIdx.x * 256 + threadIdx.x;
    if (i < Nn * 64) {
        int n = i >> 6, c = i & 63;
        atomicAdd(&pool[(size_t)batch[n] * 64 + c], h[i]);
    }
}

__global__ void k_out(const float* __restrict__ pool, const float* __restrict__ cnt,
    const float* __restrict__ W, const float* __restrict__ B, float* __restrict__ out)
{
    int g = threadIdx.x;
    if (g < 64) {
        float acc = 0.f;
        for (int c = 0; c < 64; c++) acc += pool[g * 64 + c] * W[c];
        out[g] = acc / fmaxf(cnt[g], 1.f) + B[0];
    }
}

// ---------------------------------------------------------------- launch

extern "C" void kernel_launch(void* const* d_in, const int* in_sizes, int n_in,
                              void* d_out, int out_size, void* d_ws, size_t ws_size,
                              hipStream_t stream)
{
    const float* x        = (const float*)d_in[0];
    const float* pos      = (const float*)d_in[1];
    const float* ea       = (const float*)d_in[2];
    const int*   ei       = (const int*)  d_in[3];
    const int*   batch    = (const int*)  d_in[4];
    const float* lin_in_w = (const float*)d_in[5];
    const float* lin_in_b = (const float*)d_in[6];
    const float* lin_pr_w = (const float*)d_in[7];
    const float* lin_pr_b = (const float*)d_in[8];
    const float* msg_w1   = (const float*)d_in[9];
    const float* msg_b1   = (const float*)d_in[10];
    const float* msg_g1   = (const float*)d_in[11];
    const float* msg_be1  = (const float*)d_in[12];
    const float* msg_w2   = (const float*)d_in[13];
    const float* msg_b2   = (const float*)d_in[14];
    const float* msg_g2   = (const float*)d_in[15];
    const float* msg_be2  = (const float*)d_in[16];
    const float* pos_w1   = (const float*)d_in[17];
    const float* pos_b1   = (const float*)d_in[18];
    const float* pos_g    = (const float*)d_in[19];
    const float* pos_be   = (const float*)d_in[20];
    const float* pos_w2   = (const float*)d_in[21];
    const float* pos_b2   = (const float*)d_in[22];
    const float* upd_w1   = (const float*)d_in[23];
    const float* upd_b1   = (const float*)d_in[24];
    const float* upd_g1   = (const float*)d_in[25];
    const float* upd_be1  = (const float*)d_in[26];
    const float* upd_w2   = (const float*)d_in[27];
    const float* upd_b2   = (const float*)d_in[28];
    const float* upd_g2   = (const float*)d_in[29];
    const float* upd_be2  = (const float*)d_in[30];
    float* out = (float*)d_out;

    float* ws = (float*)d_ws;
    size_t o = 0;
    float* h    = ws + o; o += (size_t)Nn * 64;
    u16*   ybuf = (u16*)(ws + o); o += (size_t)Ee * 64;  // bf16, uses half the slot
    float* yn   = ws + o; o += (size_t)Nn * 64;
    float* magg = ws + o; o += (size_t)Nn * 64;   // magg + pagg contiguous (one memset)
    float* pagg = ws + o; o += (size_t)Nn * 3;
    float* pws  = ws + o; o += (size_t)Nn * 3;
    float* stats= ws + o; o += 1280;              // stats..deg contiguous (one memset)
    float* pool = ws + o; o += 64 * 64;
    float* cnt  = ws + o; o += 64;
    float* deg  = ws + o; o += Nn;
    if (ws_size < o * sizeof(float)) return;

    hipMemsetAsync(stats, 0, (size_t)(1280 + 64 * 64 + 64 + Nn) * sizeof(float), stream);
    k_lin_in<<<(Nn * 64 + 255) / 256, 256, 0, stream>>>(x, lin_in_w, lin_in_b, h);
    k_deg<<<(Ee + 255) / 256, 256, 0, stream>>>(ei, deg);
    k_cnt<<<(Nn + 255) / 256, 256, 0, stream>>>(batch, cnt);

    for (int l = 0; l < 2; l++) {
        hipMemsetAsync(magg, 0, ((size_t)Nn * 64 + (size_t)Nn * 3) * sizeof(float), stream);
        const float* pc = (l == 0) ? pos : pws;
        float* st = stats + (size_t)l * 5 * 128;
        k_edge_lin1<<<512, 256, 0, stream>>>(h, pc, ea, ei,
            msg_w1 + (size_t)l * KIN * 64, msg_b1 + l * 64, ybuf, st + 0 * 128);
        k_edge_lin64<0><<<1024, 256, 0, stream>>>(st + 0 * 128, msg_g1 + l * 64, msg_be1 + l * 64,
            msg_w2 + (size_t)l * 64 * 64, msg_b2 + l * 64, ei, nullptr, ybuf, st + 1 * 128);
        k_edge_lin64<1><<<1024, 256, 0, stream>>>(st + 1 * 128, msg_g2 + l * 64, msg_be2 + l * 64,
            pos_w1 + (size_t)l * 64 * 64, pos_b1 + l * 64, ei, magg, ybuf, st + 2 * 128);
        k_pos2<<<(Ee + 255) / 256, 256, 0, stream>>>(st + 2 * 128, pos_g + l * 64, pos_be + l * 64,
            pos_w2 + l * 64, pos_b2 + l, pc, ei, ybuf, pagg);
        k_node_lin1<<<782, 256, 0, stream>>>(h, magg,
            upd_w1 + (size_t)l * 128 * 64, upd_b1 + l * 64, yn, st + 3 * 128);
        k_node_lin64<<<782, 256, 0, stream>>>(st + 3 * 128, upd_g1 + l * 64, upd_be1 + l * 64,
            upd_w2 + (size_t)l * 64 * 64, upd_b2 + l * 64, yn, st + 4 * 128);
        k_node_update<<<(Nn * 64 + 255) / 256, 256, 0, stream>>>(st + 4 * 128,
            upd_g2 + l * 64, upd_be2 + l * 64, yn, h, pc, pws, pagg, deg);
    }
    k_pool<<<(Nn * 64 + 255) / 256, 256, 0, stream>>>(batch, h, pool);
    k_out<<<1, 64, 0, stream>>>(pool, cnt, lin_pr_w, lin_pr_b, out);
}